// Round 3
// baseline (3851.477 us; speedup 1.0000x reference)
//
#include <hip/hip_runtime.h>
#include <hip/hip_fp16.h>

typedef _Float16 f16;
typedef _Float16 f16x8 __attribute__((ext_vector_type(8)));
typedef float f32x4 __attribute__((ext_vector_type(4)));

#define DEV static __device__ __forceinline__

// LDS-only barrier — keeps global loads in flight.
DEV void lds_barrier() {
  asm volatile("s_waitcnt lgkmcnt(0)" ::: "memory");
  __builtin_amdgcn_s_barrier();
  asm volatile("" ::: "memory");
}
// Full-drain barrier (global stores visible before crossing).
DEV void drain_barrier() {
  asm volatile("s_waitcnt vmcnt(0) lgkmcnt(0)" ::: "memory");
  __builtin_amdgcn_s_barrier();
  asm volatile("" ::: "memory");
}
// Control-only barrier (no waitcnt — prefetch survives).
DEV void ctrl_barrier() {
  asm volatile("" ::: "memory");
  __builtin_amdgcn_s_barrier();
  asm volatile("" ::: "memory");
}

// ---------------------------------------------------------------- conv1
__global__ __launch_bounds__(256) void k_conv1(
    const float* __restrict__ in, const float* __restrict__ w,
    const float* __restrict__ bias, f16* __restrict__ out)
{
  int idx = blockIdx.x*256 + threadIdx.x;
  int co = idx & 63;
  int ow = (idx >> 6) % 40;
  int oh = ((idx >> 6) / 40) % 1024;
  int b  = idx / (64*40*1024);
  float acc = bias[co];
#pragma unroll
  for (int kh=0; kh<3; kh++) {
    int ih = oh*2 + kh;
    if (ih >= 2048) continue;
#pragma unroll
    for (int kw=0; kw<3; kw++) {
      int iw = ow*2 + kw;
      if (iw >= 80) continue;
      acc += in[(b*2048 + ih)*80 + iw] * w[(kh*3+kw)*64 + co];
    }
  }
  out[idx] = (f16)fmaxf(acc, 0.f);
}

// ---------------------------------------------------------------- weight convert+transpose
__global__ __launch_bounds__(256) void k_wcvt(
    const float* __restrict__ w, f16* __restrict__ wt)
{
  int idx = blockIdx.x*256 + threadIdx.x;
  if (idx >= 38912) return;
  f16 v = (f16)0.f;
  if (idx < 38400) {
    int n = idx / 600, k = idx % 600;
    if (k < 576) v = (f16)w[k*64 + n];
  }
  wt[idx] = v;
}

// ---------------------------------------------------------------- conv2 as implicit GEMM (MFMA fp16)
__global__ __launch_bounds__(256) void k_conv2m(
    const f16* __restrict__ x1f, const f16* __restrict__ wt,
    const float* __restrict__ bias, float* __restrict__ out)
{
  __shared__ f16 Bt[38912];
  const int tid = threadIdx.x;
  for (int it = 0; it < 19; ++it) {
    const f16* g = wt + it*2048 + tid*8;
    f16* l = Bt + it*2048 + tid*8;
    __builtin_amdgcn_global_load_lds(
        (const __attribute__((address_space(1))) void*)g,
        (__attribute__((address_space(3))) void*)l, 16, 0, 0);
  }
  __syncthreads();

  const int wave = tid >> 6, l = tid & 63;
  const int lrow = l & 15, lk = l >> 4;
  const int m0 = blockIdx.x*128 + wave*32;

  const int mA = m0 + lrow, mB = m0 + 16 + lrow;
  int bA = mA/10240, rA = mA%10240, ohA = rA/20, owA = rA%20;
  int bB = mB/10240, rB = mB%10240, ohB = rB/20, owB = rB%20;
  const f16* pA = x1f + ((size_t)((bA*1024 + ohA*2)*40 + owA*2))*64;
  const f16* pB = x1f + ((size_t)((bB*1024 + ohB*2)*40 + owB*2))*64;

  f32x4 acc[2][4];
#pragma unroll
  for (int i=0;i<2;i++)
#pragma unroll
    for (int j=0;j<4;j++) acc[i][j] = (f32x4){0.f,0.f,0.f,0.f};

  const f16x8 zero8 = {};
#pragma unroll
  for (int kk=0; kk<18; ++kk) {
    const int tap = kk >> 1;
    const int kh = tap/3, kw = tap%3;
    const int ci0 = ((kk&1)<<5) + lk*8;
    const int off = (kh*40 + kw)*64 + ci0;
    const bool okA = (ohA*2+kh < 1024) && (owA*2+kw < 40);
    const bool okB = (ohB*2+kh < 1024) && (owB*2+kw < 40);
    f16x8 a0 = okA ? *(const f16x8*)(pA + off) : zero8;
    f16x8 a1 = okB ? *(const f16x8*)(pB + off) : zero8;
#pragma unroll
    for (int nf=0; nf<4; ++nf) {
      f16x8 bb = *(const f16x8*)&Bt[(nf*16 + lrow)*600 + kk*32 + lk*8];
      acc[0][nf] = __builtin_amdgcn_mfma_f32_16x16x32_f16(a0, bb, acc[0][nf], 0,0,0);
      acc[1][nf] = __builtin_amdgcn_mfma_f32_16x16x32_f16(a1, bb, acc[1][nf], 0,0,0);
    }
  }
#pragma unroll
  for (int nf=0; nf<4; ++nf) {
    const int n = nf*16 + lrow;
    const float bi = bias[n];
#pragma unroll
    for (int mf=0; mf<2; ++mf)
#pragma unroll
      for (int r=0; r<4; ++r) {
        int mrow = m0 + mf*16 + lk*4 + r;
        out[(size_t)mrow*64 + n] = fmaxf(acc[mf][nf][r] + bi, 0.f);
      }
  }
}

// ---------------------------------------------------------------- proj
__global__ __launch_bounds__(256) void k_proj(
    const float* __restrict__ x, const float* __restrict__ pw,
    const float* __restrict__ pb, float* __restrict__ out)
{
  int bt = blockIdx.x;
  int tid = threadIdx.x;
  int j = tid >> 4;
  int l = tid & 15;
  const float* xr = x + (size_t)bt*1280;
  float s = 0.f;
  for (int k=0; k<80; k++) {
    int f = l + 16*k;
    s += xr[f] * pw[f*16 + j];
  }
  s += __shfl_xor(s, 1, 16); s += __shfl_xor(s, 2, 16);
  s += __shfl_xor(s, 4, 16); s += __shfl_xor(s, 8, 16);
  if (l == 0) out[bt*16 + j] = s + pb[j];
}

// ------------------------------------------- primary caps
__global__ __launch_bounds__(128) void k_primary(
    const float* __restrict__ emb0,
    const float* __restrict__ w0, const float* __restrict__ b0,
    const float* __restrict__ w1, const float* __restrict__ b1,
    const float* __restrict__ g, const float* __restrict__ be,
    const int* __restrict__ lens, float* __restrict__ out)
{
  int bt = blockIdx.x;
  int b = bt >> 9, t = bt & 511;
  int tid = threadIdx.x;
  int c = tid & 7, j = tid >> 3;
  __shared__ float rows[3][16];
  __shared__ float red[4];
  if (tid < 48) {
    int kh = tid / 16, jj = tid % 16;
    int ts = t + kh - 1;
    rows[kh][jj] = (ts >= 0 && ts < 512) ? emb0[(b*512+ts)*16 + jj] : 0.f;
  }
  __syncthreads();
  float a0 = b0[c], a1 = b1[c];
#pragma unroll
  for (int kh=0; kh<3; kh++)
#pragma unroll
    for (int kw=0; kw<3; kw++) {
      int jj = j + kw - 1;
      if (jj < 0 || jj >= 16) continue;
      float xv = rows[kh][jj];
      a0 += xv * w0[(kh*3+kw)*8 + c];
      a1 += xv * w1[(kh*3+kw)*8 + c];
    }
  float e = fmaxf(a0, a1);
  int valid = (lens[b] + 3) >> 2;
  if (t >= valid) e = 0.f;
  float sq = e*e;
  sq += __shfl_xor(sq, 1, 8); sq += __shfl_xor(sq, 2, 8); sq += __shfl_xor(sq, 4, 8);
  float val = e * (sq / (1.f + sq)) * rsqrtf(sq + 1e-9f);
  float s1 = val, s2 = val*val;
#pragma unroll
  for (int m=1;m<64;m<<=1){ s1 += __shfl_xor(s1,m,64); s2 += __shfl_xor(s2,m,64); }
  if ((tid & 63) == 0){ red[(tid>>6)*2] = s1; red[(tid>>6)*2+1] = s2; }
  __syncthreads();
  float S1 = red[0]+red[2], S2 = red[1]+red[3];
  float mean = S1/128.f;
  float var  = S2/128.f - mean*mean;
  out[(size_t)bt*128 + tid] = (val-mean)*rsqrtf(var+1e-3f)*g[tid] + be[tid];
}

// ---------------------------------------------------------------- generic LN over 128
__global__ __launch_bounds__(128) void k_ln128(
    const float* __restrict__ in, const float* __restrict__ g,
    const float* __restrict__ be, float* __restrict__ out)
{
  int bt = blockIdx.x, tid = threadIdx.x;
  float x = in[(size_t)bt*128 + tid];
  __shared__ float red[4];
  float s1 = x, s2 = x*x;
#pragma unroll
  for (int m=1;m<64;m<<=1){ s1 += __shfl_xor(s1,m,64); s2 += __shfl_xor(s2,m,64); }
  if ((tid & 63) == 0){ red[(tid>>6)*2] = s1; red[(tid>>6)*2+1] = s2; }
  __syncthreads();
  float S1 = red[0]+red[2], S2 = red[1]+red[3];
  float mean = S1/128.f;
  float var  = S2/128.f - mean*mean;
  out[(size_t)bt*128 + tid] = (x-mean)*rsqrtf(var+1e-3f)*g[tid] + be[tid];
}

// ---------------------------------------------------------------- u_hat precompute
template<int CO, int CD>
__global__ __launch_bounds__(256) void k_uhat(
    const float* __restrict__ src, const float* __restrict__ W,
    const float* __restrict__ Bs, f16* __restrict__ out)
{
  constexpr int NP = 80*CO;
  int wid = __builtin_amdgcn_readfirstlane(blockIdx.x*4 + (threadIdx.x >> 6));
  int lane = threadIdx.x & 63;
  int n   = wid % 80;
  int btc = wid / 80;
  int bt = btc*64 + lane;
  int b = bt >> 9, t = bt & 511;
  int k = n >> 4, i = n & 15;
  int ts = t + k - 2;
  float x[8];
  if (ts >= 0 && ts < 512) {
    const float* xr = src + ((size_t)(b*512+ts)*16 + i)*8;
    f32x4 x0 = *(const f32x4*)xr;
    f32x4 x1 = *(const f32x4*)(xr+4);
#pragma unroll
    for (int q=0;q<4;q++){ x[q]=x0[q]; x[4+q]=x1[q]; }
  } else {
#pragma unroll
    for (int q=0;q<8;q++) x[q]=0.f;
  }
  const float* Wn = W  + (size_t)n*CO*CD*8;
  const float* Bn = Bs + (size_t)n*CO*CD;
  for (int o=0; o<CO; o++) {
    alignas(16) f16 res[CD];
#pragma unroll
    for (int p=0;p<CD;p++) {
      float a = Bn[o*CD+p];
#pragma unroll
      for (int q=0;q<8;q++) a += Wn[(o*CD+p)*8+q]*x[q];
      res[p] = (f16)a;
    }
    f16* op = out + ((size_t)bt*NP + (size_t)n*CO + o)*CD;
    *(uint4*)op = *(const uint4*)res;
    if constexpr (CD==16) *((uint4*)op+1) = *((const uint4*)res+1);
  }
}

// ---------------------------------------------------------------- split-n routing scan
// 5 groups/batch, one window-slot (16 n) per group, 1 n per thread.
// Per-step cross-group exchange of partial s[o,p] via LLC (AGENT atomics),
// double-buffered by step parity; per-batch monotonic counter, zeroed per launch.
template<int CO, int CD, bool MASK>
__global__ __launch_bounds__(CO*16, 1) void k_scan2(
    const f16* __restrict__ uh, float* __restrict__ vseq,
    float* __restrict__ ex, int* __restrict__ ctr, int T)
{
  constexpr int G = 5;
  constexpr int TH = CO*16;
  constexpr int NP = 80*CO;
  constexpr int NV = CD/8;
  constexpr int QN = CO*CD;
  constexpr int CDP = CD + 4;          // 16B-aligned padded row

  const int bid = blockIdx.x;
  const int b = bid / G, g = bid % G;
  const int tid = threadIdx.x;
  const int o = tid % CO, j = tid / CO;
  const int n = g*16 + j;

  __shared__ float part[TH*CDP];
  __shared__ float smat[CO*CDP];

  const f16* __restrict__ ub = uh + ((size_t)b*T*NP + (size_t)(n*CO + o))*CD;
  float* __restrict__ vb  = vseq + (size_t)b*T*QN;
  float* __restrict__ exb = ex + (size_t)b*2*G*QN;
  int* cp = ctr + b;

  float v[CD];
#pragma unroll
  for (int p=0;p<CD;p++) v[p] = 0.f;

  f16x8 Uc[NV], Un[NV];
#pragma unroll
  for (int q=0;q<NV;q++) Uc[q] = *(const f16x8*)(ub + q*8);

  for (int t=0; t<T; ++t) {
    // ---- logits (v_fma_mix: f32 += f16*f32)
    float lg = 0.f;
#pragma unroll
    for (int q=0;q<NV;q++)
#pragma unroll
      for (int z=0;z<8;z++)
        lg += (float)Uc[q][z] * v[q*8+z];
    if (MASK && o==0) lg -= 1e9f;
    // ---- softmax over o (CO consecutive lanes)
    float mx = lg;
#pragma unroll
    for (int m=1;m<CO;m<<=1) mx = fmaxf(mx, __shfl_xor(mx, m, CO));
    float exn = __expf(lg - mx);
    float sm = exn;
#pragma unroll
    for (int m=1;m<CO;m<<=1) sm += __shfl_xor(sm, m, CO);
    float c = exn / sm;
    // ---- weighted u -> LDS
    float* pr = part + tid*CDP;
#pragma unroll
    for (int p4=0;p4<CD;p4+=4) {
      f32x4 w4;
#pragma unroll
      for (int z=0;z<4;z++) w4[z] = c * (float)Uc[(p4+z)/8][(p4+z)&7];
      *(f32x4*)(pr + p4) = w4;
    }
    lds_barrier();
    // ---- j-reduce + exchange store
    if (tid < QN) {
      const int o2 = tid / CD, p2 = tid % CD;
      float s = 0.f;
#pragma unroll
      for (int jj=0;jj<16;jj++) s += part[(jj*CO+o2)*CDP + p2];
      __hip_atomic_store(&exb[((size_t)(t&1)*G + g)*QN + tid], s,
                         __ATOMIC_RELAXED, __HIP_MEMORY_SCOPE_AGENT);
    }
    drain_barrier();                   // ex stores globally visible
    // ---- prefetch next u (survives the control barrier below)
    {
      const f16* nb = ub + (size_t)(t+1 < T ? t+1 : t)*NP*CD;
#pragma unroll
      for (int q=0;q<NV;q++) Un[q] = *(const f16x8*)(nb + q*8);
    }
    // ---- arrive + spin (thread 0 only)
    if (tid == 0) {
      __hip_atomic_fetch_add(cp, 1, __ATOMIC_RELEASE, __HIP_MEMORY_SCOPE_AGENT);
      const int target = G*(t+1);
      while (__hip_atomic_load(cp, __ATOMIC_ACQUIRE, __HIP_MEMORY_SCOPE_AGENT) < target)
        __builtin_amdgcn_s_sleep(1);
    }
    ctrl_barrier();
    // ---- gather partials + squash + publish v
    if (tid < QN) {
      float s = 0.f;
#pragma unroll
      for (int g2=0; g2<G; ++g2)
        s += __hip_atomic_load(&exb[((size_t)(t&1)*G + g2)*QN + tid],
                               __ATOMIC_RELAXED, __HIP_MEMORY_SCOPE_AGENT);
      float sq = s*s;
#pragma unroll
      for (int m=1;m<CD;m<<=1) sq += __shfl_xor(sq, m, CD);
      float f = (sq/(1.f+sq)) * rsqrtf(sq + 1e-9f);
      float vn = s * f;
      const int o2 = tid / CD, p2 = tid % CD;
      smat[o2*CDP + p2] = vn;
      vb[(size_t)t*QN + tid] = vn;
    }
    lds_barrier();
#pragma unroll
    for (int p4=0;p4<CD;p4+=4)
      *(f32x4*)(v+p4) = *(const f32x4*)(smat + o*CDP + p4);
#pragma unroll
    for (int q=0;q<NV;q++) Uc[q] = Un[q];
  }
}

// ---------------------------------------------------------------- final: LN512 -> length -> LN32
__global__ __launch_bounds__(512) void k_final(
    const float* __restrict__ v1,
    const float* __restrict__ g1, const float* __restrict__ b1,
    const float* __restrict__ g2, const float* __restrict__ b2,
    float* __restrict__ out)
{
  int bt = blockIdx.x;
  int tid = threadIdx.x;
  float x = v1[(size_t)bt*512 + tid];
  __shared__ float red[16];
  __shared__ float Ls[32];
  float s1 = x, s2 = x*x;
#pragma unroll
  for (int m=1;m<64;m<<=1){ s1 += __shfl_xor(s1,m,64); s2 += __shfl_xor(s2,m,64); }
  if ((tid & 63) == 0){ red[(tid>>6)*2] = s1; red[(tid>>6)*2+1] = s2; }
  __syncthreads();
  float S1 = 0.f, S2 = 0.f;
#pragma unroll
  for (int i=0;i<8;i++){ S1 += red[2*i]; S2 += red[2*i+1]; }
  float mean = S1/512.f, var = S2/512.f - mean*mean;
  float y = (x-mean)*rsqrtf(var+1e-3f)*g1[tid] + b1[tid];
  float ss = y*y;
  ss += __shfl_xor(ss,1,16); ss += __shfl_xor(ss,2,16);
  ss += __shfl_xor(ss,4,16); ss += __shfl_xor(ss,8,16);
  float L = sqrtf(ss + 1e-9f);
  if ((tid & 15) == 0) Ls[tid >> 4] = L;
  __syncthreads();
  if (tid < 32) {
    float l = Ls[tid];
    float t1 = l, t2 = l*l;
#pragma unroll
    for (int m=1;m<32;m<<=1){ t1 += __shfl_xor(t1,m,32); t2 += __shfl_xor(t2,m,32); }
    float mn = t1/32.f, vr = t2/32.f - mn*mn;
    out[(size_t)bt*32 + tid] = (l-mn)*rsqrtf(vr+1e-3f)*g2[tid] + b2[tid];
  }
}

// ---------------------------------------------------------------- workspace layout
static const size_t OFF_X1F   = 0;            // 20,971,520 B f16 [4,1024,40,64]
static const size_t OFF_WT16  = 20971520;     //     77,824 B f16 [64][600]
static const size_t OFF_X2    = 21049344;     // 10,485,760 B f32 [4,512,20,64]
static const size_t OFF_EMB0  = 31535104;     //    131,072 B f32 [4,512,16]
static const size_t OFF_UH0   = 31666176;     // 41,943,040 B f16 [4,512,1280,8]
static const size_t OFF_UH1   = 0;            // 167,772,160 B f16 [4,512,2560,16]
static const size_t OFF_EMBLN = 167772160;    //  1,048,576 B f32 (dead before scan0)
static const size_t OFF_V0    = 167772160;    //  1,048,576 B f32 (reuses EMBLN slot)
static const size_t OFF_V0LN  = 168820736;    //  1,048,576 B f32
static const size_t OFF_V1    = 169869312;    //  4,194,304 B f32 [4,512,32,16]
static const size_t OFF_EX0   = 174063616;    //     20,480 B f32 [4][2][5][128]
static const size_t OFF_EX1   = 174084096;    //     81,920 B f32 [4][2][5][512]
static const size_t OFF_CTR   = 174166016;    //         32 B int [8]
static const size_t WS_NEED   = 174166048;

extern "C" void kernel_launch(void* const* d_in, const int* in_sizes, int n_in,
                              void* d_out, int out_size, void* d_ws, size_t ws_size,
                              hipStream_t stream) {
  (void)in_sizes; (void)n_in; (void)out_size;
  if (ws_size < WS_NEED) return;

  const float* inputs = (const float*)d_in[0];
  const int*   lens   = (const int*)d_in[1];
  const float* c1w=(const float*)d_in[2],  *c1b=(const float*)d_in[3];
  const float* c2w=(const float*)d_in[4],  *c2b=(const float*)d_in[5];
  const float* pw =(const float*)d_in[6],  *pb =(const float*)d_in[7];
  const float* e0w=(const float*)d_in[8],  *e0b=(const float*)d_in[9];
  const float* e1w=(const float*)d_in[10], *e1b=(const float*)d_in[11];
  const float* lnig=(const float*)d_in[12],*lnib=(const float*)d_in[13];
  const float* W0=(const float*)d_in[14],  *B0=(const float*)d_in[15];
  const float* W1=(const float*)d_in[16],  *B1=(const float*)d_in[17];
  const float* lnm0g=(const float*)d_in[18],*lnm0b=(const float*)d_in[19];
  const float* lnm1g=(const float*)d_in[20],*lnm1b=(const float*)d_in[21];
  const float* lnog=(const float*)d_in[22], *lnob=(const float*)d_in[23];

  char* ws = (char*)d_ws;
  f16*   x1f   = (f16*)  (ws + OFF_X1F);
  f16*   wt16  = (f16*)  (ws + OFF_WT16);
  float* x2    = (float*)(ws + OFF_X2);
  float* emb0  = (float*)(ws + OFF_EMB0);
  f16*   uh0   = (f16*)  (ws + OFF_UH0);
  f16*   uh1   = (f16*)  (ws + OFF_UH1);
  float* embln = (float*)(ws + OFF_EMBLN);
  float* v0    = (float*)(ws + OFF_V0);
  float* v0ln  = (float*)(ws + OFF_V0LN);
  float* v1    = (float*)(ws + OFF_V1);
  float* ex0   = (float*)(ws + OFF_EX0);
  float* ex1   = (float*)(ws + OFF_EX1);
  int*   ctr   = (int*)  (ws + OFF_CTR);

  hipMemsetAsync(ws + OFF_CTR, 0, 32, stream);

  k_conv1<<<40960, 256, 0, stream>>>(inputs, c1w, c1b, x1f);
  k_wcvt <<<152, 256, 0, stream>>>(c2w, wt16);
  k_conv2m<<<320, 256, 0, stream>>>(x1f, wt16, c2b, x2);
  k_proj <<<2048, 256, 0, stream>>>(x2, pw, pb, emb0);
  k_primary<<<2048, 128, 0, stream>>>(emb0, e0w, e0b, e1w, e1b, lnig, lnib, lens, embln);
  k_uhat<16,8><<<640, 256, 0, stream>>>(embln, W0, B0, uh0);
  k_scan2<16,8,false><<<20, 256, 0, stream>>>(uh0, v0, ex0, ctr, 512);
  k_ln128<<<2048, 128, 0, stream>>>(v0, lnm0g, lnm0b, v0ln);
  k_uhat<32,16><<<640, 256, 0, stream>>>(v0ln, W1, B1, uh1);
  k_scan2<32,16,true><<<20, 512, 0, stream>>>(uh1, v1, ex1, ctr+4, 512);
  k_final<<<2048, 512, 0, stream>>>(v1, lnm1g, lnm1b, lnog, lnob, (float*)d_out);
}

// Round 4
// 3106.818 us; speedup vs baseline: 1.2397x; 1.2397x over previous
//
#include <hip/hip_runtime.h>
#include <hip/hip_fp16.h>

typedef _Float16 f16;
typedef _Float16 f16x8 __attribute__((ext_vector_type(8)));
typedef float f32x4 __attribute__((ext_vector_type(4)));

#define DEV static __device__ __forceinline__

// LDS-only barrier — keeps global loads/stores in flight.
DEV void lds_barrier() {
  asm volatile("s_waitcnt lgkmcnt(0)" ::: "memory");
  __builtin_amdgcn_s_barrier();
  asm volatile("" ::: "memory");
}

// ---------------------------------------------------------------- conv1
__global__ __launch_bounds__(256) void k_conv1(
    const float* __restrict__ in, const float* __restrict__ w,
    const float* __restrict__ bias, f16* __restrict__ out)
{
  int idx = blockIdx.x*256 + threadIdx.x;
  int co = idx & 63;
  int ow = (idx >> 6) % 40;
  int oh = ((idx >> 6) / 40) % 1024;
  int b  = idx / (64*40*1024);
  float acc = bias[co];
#pragma unroll
  for (int kh=0; kh<3; kh++) {
    int ih = oh*2 + kh;
    if (ih >= 2048) continue;
#pragma unroll
    for (int kw=0; kw<3; kw++) {
      int iw = ow*2 + kw;
      if (iw >= 80) continue;
      acc += in[(b*2048 + ih)*80 + iw] * w[(kh*3+kw)*64 + co];
    }
  }
  out[idx] = (f16)fmaxf(acc, 0.f);
}

// ---------------------------------------------------------------- weight convert+transpose
__global__ __launch_bounds__(256) void k_wcvt(
    const float* __restrict__ w, f16* __restrict__ wt)
{
  int idx = blockIdx.x*256 + threadIdx.x;
  if (idx >= 38912) return;
  f16 v = (f16)0.f;
  if (idx < 38400) {
    int n = idx / 600, k = idx % 600;
    if (k < 576) v = (f16)w[k*64 + n];
  }
  wt[idx] = v;
}

// ---------------------------------------------------------------- conv2 as implicit GEMM (MFMA fp16)
__global__ __launch_bounds__(256) void k_conv2m(
    const f16* __restrict__ x1f, const f16* __restrict__ wt,
    const float* __restrict__ bias, float* __restrict__ out)
{
  __shared__ f16 Bt[38912];
  const int tid = threadIdx.x;
  for (int it = 0; it < 19; ++it) {
    const f16* g = wt + it*2048 + tid*8;
    f16* l = Bt + it*2048 + tid*8;
    __builtin_amdgcn_global_load_lds(
        (const __attribute__((address_space(1))) void*)g,
        (__attribute__((address_space(3))) void*)l, 16, 0, 0);
  }
  __syncthreads();

  const int wave = tid >> 6, l = tid & 63;
  const int lrow = l & 15, lk = l >> 4;
  const int m0 = blockIdx.x*128 + wave*32;

  const int mA = m0 + lrow, mB = m0 + 16 + lrow;
  int bA = mA/10240, rA = mA%10240, ohA = rA/20, owA = rA%20;
  int bB = mB/10240, rB = mB%10240, ohB = rB/20, owB = rB%20;
  const f16* pA = x1f + ((size_t)((bA*1024 + ohA*2)*40 + owA*2))*64;
  const f16* pB = x1f + ((size_t)((bB*1024 + ohB*2)*40 + owB*2))*64;

  f32x4 acc[2][4];
#pragma unroll
  for (int i=0;i<2;i++)
#pragma unroll
    for (int j=0;j<4;j++) acc[i][j] = (f32x4){0.f,0.f,0.f,0.f};

  const f16x8 zero8 = {};
#pragma unroll
  for (int kk=0; kk<18; ++kk) {
    const int tap = kk >> 1;
    const int kh = tap/3, kw = tap%3;
    const int ci0 = ((kk&1)<<5) + lk*8;
    const int off = (kh*40 + kw)*64 + ci0;
    const bool okA = (ohA*2+kh < 1024) && (owA*2+kw < 40);
    const bool okB = (ohB*2+kh < 1024) && (owB*2+kw < 40);
    f16x8 a0 = okA ? *(const f16x8*)(pA + off) : zero8;
    f16x8 a1 = okB ? *(const f16x8*)(pB + off) : zero8;
#pragma unroll
    for (int nf=0; nf<4; ++nf) {
      f16x8 bb = *(const f16x8*)&Bt[(nf*16 + lrow)*600 + kk*32 + lk*8];
      acc[0][nf] = __builtin_amdgcn_mfma_f32_16x16x32_f16(a0, bb, acc[0][nf], 0,0,0);
      acc[1][nf] = __builtin_amdgcn_mfma_f32_16x16x32_f16(a1, bb, acc[1][nf], 0,0,0);
    }
  }
#pragma unroll
  for (int nf=0; nf<4; ++nf) {
    const int n = nf*16 + lrow;
    const float bi = bias[n];
#pragma unroll
    for (int mf=0; mf<2; ++mf)
#pragma unroll
      for (int r=0; r<4; ++r) {
        int mrow = m0 + mf*16 + lk*4 + r;
        out[(size_t)mrow*64 + n] = fmaxf(acc[mf][nf][r] + bi, 0.f);
      }
  }
}

// ---------------------------------------------------------------- proj
__global__ __launch_bounds__(256) void k_proj(
    const float* __restrict__ x, const float* __restrict__ pw,
    const float* __restrict__ pb, float* __restrict__ out)
{
  int bt = blockIdx.x;
  int tid = threadIdx.x;
  int j = tid >> 4;
  int l = tid & 15;
  const float* xr = x + (size_t)bt*1280;
  float s = 0.f;
  for (int k=0; k<80; k++) {
    int f = l + 16*k;
    s += xr[f] * pw[f*16 + j];
  }
  s += __shfl_xor(s, 1, 16); s += __shfl_xor(s, 2, 16);
  s += __shfl_xor(s, 4, 16); s += __shfl_xor(s, 8, 16);
  if (l == 0) out[bt*16 + j] = s + pb[j];
}

// ------------------------------------------- primary caps
__global__ __launch_bounds__(128) void k_primary(
    const float* __restrict__ emb0,
    const float* __restrict__ w0, const float* __restrict__ b0,
    const float* __restrict__ w1, const float* __restrict__ b1,
    const float* __restrict__ g, const float* __restrict__ be,
    const int* __restrict__ lens, float* __restrict__ out)
{
  int bt = blockIdx.x;
  int b = bt >> 9, t = bt & 511;
  int tid = threadIdx.x;
  int c = tid & 7, j = tid >> 3;
  __shared__ float rows[3][16];
  __shared__ float red[4];
  if (tid < 48) {
    int kh = tid / 16, jj = tid % 16;
    int ts = t + kh - 1;
    rows[kh][jj] = (ts >= 0 && ts < 512) ? emb0[(b*512+ts)*16 + jj] : 0.f;
  }
  __syncthreads();
  float a0 = b0[c], a1 = b1[c];
#pragma unroll
  for (int kh=0; kh<3; kh++)
#pragma unroll
    for (int kw=0; kw<3; kw++) {
      int jj = j + kw - 1;
      if (jj < 0 || jj >= 16) continue;
      float xv = rows[kh][jj];
      a0 += xv * w0[(kh*3+kw)*8 + c];
      a1 += xv * w1[(kh*3+kw)*8 + c];
    }
  float e = fmaxf(a0, a1);
  int valid = (lens[b] + 3) >> 2;
  if (t >= valid) e = 0.f;
  float sq = e*e;
  sq += __shfl_xor(sq, 1, 8); sq += __shfl_xor(sq, 2, 8); sq += __shfl_xor(sq, 4, 8);
  float val = e * (sq / (1.f + sq)) * rsqrtf(sq + 1e-9f);
  float s1 = val, s2 = val*val;
#pragma unroll
  for (int m=1;m<64;m<<=1){ s1 += __shfl_xor(s1,m,64); s2 += __shfl_xor(s2,m,64); }
  if ((tid & 63) == 0){ red[(tid>>6)*2] = s1; red[(tid>>6)*2+1] = s2; }
  __syncthreads();
  float S1 = red[0]+red[2], S2 = red[1]+red[3];
  float mean = S1/128.f;
  float var  = S2/128.f - mean*mean;
  out[(size_t)bt*128 + tid] = (val-mean)*rsqrtf(var+1e-3f)*g[tid] + be[tid];
}

// ---------------------------------------------------------------- generic LN over 128
__global__ __launch_bounds__(128) void k_ln128(
    const float* __restrict__ in, const float* __restrict__ g,
    const float* __restrict__ be, float* __restrict__ out)
{
  int bt = blockIdx.x, tid = threadIdx.x;
  float x = in[(size_t)bt*128 + tid];
  __shared__ float red[4];
  float s1 = x, s2 = x*x;
#pragma unroll
  for (int m=1;m<64;m<<=1){ s1 += __shfl_xor(s1,m,64); s2 += __shfl_xor(s2,m,64); }
  if ((tid & 63) == 0){ red[(tid>>6)*2] = s1; red[(tid>>6)*2+1] = s2; }
  __syncthreads();
  float S1 = red[0]+red[2], S2 = red[1]+red[3];
  float mean = S1/128.f;
  float var  = S2/128.f - mean*mean;
  out[(size_t)bt*128 + tid] = (x-mean)*rsqrtf(var+1e-3f)*g[tid] + be[tid];
}

// ---------------------------------------------------------------- u_hat precompute
template<int CO, int CD>
__global__ __launch_bounds__(256) void k_uhat(
    const float* __restrict__ src, const float* __restrict__ W,
    const float* __restrict__ Bs, f16* __restrict__ out)
{
  constexpr int NP = 80*CO;
  int wid = __builtin_amdgcn_readfirstlane(blockIdx.x*4 + (threadIdx.x >> 6));
  int lane = threadIdx.x & 63;
  int n   = wid % 80;
  int btc = wid / 80;
  int bt = btc*64 + lane;
  int b = bt >> 9, t = bt & 511;
  int k = n >> 4, i = n & 15;
  int ts = t + k - 2;
  float x[8];
  if (ts >= 0 && ts < 512) {
    const float* xr = src + ((size_t)(b*512+ts)*16 + i)*8;
    f32x4 x0 = *(const f32x4*)xr;
    f32x4 x1 = *(const f32x4*)(xr+4);
#pragma unroll
    for (int q=0;q<4;q++){ x[q]=x0[q]; x[4+q]=x1[q]; }
  } else {
#pragma unroll
    for (int q=0;q<8;q++) x[q]=0.f;
  }
  const float* Wn = W  + (size_t)n*CO*CD*8;
  const float* Bn = Bs + (size_t)n*CO*CD;
  for (int o=0; o<CO; o++) {
    alignas(16) f16 res[CD];
#pragma unroll
    for (int p=0;p<CD;p++) {
      float a = Bn[o*CD+p];
#pragma unroll
      for (int q=0;q<8;q++) a += Wn[(o*CD+p)*8+q]*x[q];
      res[p] = (f16)a;
    }
    f16* op = out + ((size_t)bt*NP + (size_t)n*CO + o)*CD;
    *(uint4*)op = *(const uint4*)res;
    if constexpr (CD==16) *((uint4*)op+1) = *((const uint4*)res+1);
  }
}

// ---------------------------------------------------------------- routing scan (single block per batch,
// many waves). tid -> o = tid%CO, jj = tid/CO; slots s: n = jj + s*NJ (<80).
// v kept packed f16 (smat) -> v_fma_mix consumes f16 directly.
template<int CO, int CD, int NJ, bool MASK>
__global__ __launch_bounds__(CO*NJ, 1) void k_scan3(
    const f16* __restrict__ uh, float* __restrict__ vseq, int T)
{
  constexpr int TH = CO*NJ;
  constexpr int NW = TH/64;                 // waves per block
  constexpr int NP = 80*CO;
  constexpr int QN = CO*CD;
  constexpr int SLOTS = (80 + NJ - 1)/NJ;
  constexpr int CDP = CD + 4;               // part row stride (words)
  constexpr int P2  = (CD == 16) ? 12 : 4;  // smat row stride (u32 words), 16B-aligned rows

  __shared__ float    part[NW*CO*CDP];
  __shared__ uint32_t smat[CO*P2];

  const int b   = blockIdx.x;
  const int tid = threadIdx.x;
  const int o   = tid % CO;
  const int jj  = tid / CO;
  const int wv  = tid >> 6;
  const int lane = tid & 63;

  const f16* __restrict__ ub = uh + (size_t)b*T*NP*CD;
  float* __restrict__ vb = vseq + (size_t)b*T*QN;

  // per-slot element offsets (clamped for the partial last slot)
  uint32_t uoff[SLOTS];
#pragma unroll
  for (int s=0;s<SLOTS;s++) {
    int n = jj + s*NJ;
    if (n >= 80) n = jj;                    // harmless clamp; result unused
    uoff[s] = (uint32_t)(n*CO + o)*CD;
  }

  union VH { uint32_t w[CD/2]; f16 h[CD]; uint4 q4[CD/8]; } vh;
#pragma unroll
  for (int q=0;q<CD/2;q++) vh.w[q] = 0u;

  f16x8 Ua[SLOTS][CD/8], Ub[SLOTS][CD/8];

  auto loadu = [&](f16x8 (&U)[SLOTS][CD/8], int tt) {
    const f16* base = ub + (size_t)tt*NP*CD;
#pragma unroll
    for (int s=0;s<SLOTS;s++)
#pragma unroll
      for (int q=0;q<CD/8;q++)
        U[s][q] = *(const f16x8*)(base + uoff[s] + q*8);
  };

  auto step = [&](const f16x8 (&U)[SLOTS][CD/8], int tt) {
    // ---- logits per slot (v_fma_mix: f32 += f16*f16)
    float lg[SLOTS];
#pragma unroll
    for (int s=0;s<SLOTS;s++) {
      float a0 = 0.f, a1 = 0.f;
#pragma unroll
      for (int q=0;q<CD/8;q++)
#pragma unroll
        for (int z=0;z<4;z++) {
          a0 += (float)U[s][q][2*z]   * (float)vh.h[q*8+2*z];
          a1 += (float)U[s][q][2*z+1] * (float)vh.h[q*8+2*z+1];
        }
      lg[s] = a0 + a1;
      if (MASK && o == 0) lg[s] -= 1e9f;
    }
    // ---- softmax over o (CO-lane groups), slots interleaved for ILP
    float mx[SLOTS], ex_[SLOTS], sm[SLOTS];
#pragma unroll
    for (int s=0;s<SLOTS;s++) mx[s] = lg[s];
#pragma unroll
    for (int m=1;m<CO;m<<=1)
#pragma unroll
      for (int s=0;s<SLOTS;s++) mx[s] = fmaxf(mx[s], __shfl_xor(mx[s], m, CO));
#pragma unroll
    for (int s=0;s<SLOTS;s++) { ex_[s] = __expf(lg[s]-mx[s]); sm[s] = ex_[s]; }
#pragma unroll
    for (int m=1;m<CO;m<<=1)
#pragma unroll
      for (int s=0;s<SLOTS;s++) sm[s] += __shfl_xor(sm[s], m, CO);
    // ---- weighted sum into pp
    float pp[CD];
#pragma unroll
    for (int p=0;p<CD;p++) pp[p] = 0.f;
#pragma unroll
    for (int s=0;s<SLOTS;s++) {
      bool valid = (jj + s*NJ) < 80;        // compile-time true for s<SLOTS-1
      if (valid) {
        float c = ex_[s] / sm[s];
#pragma unroll
        for (int p=0;p<CD;p++) pp[p] += c * (float)U[s][p/8][p&7];
      }
    }
    // ---- in-wave jj reduction (same-o lanes)
#pragma unroll
    for (int lvl=CO; lvl<64; lvl<<=1)
#pragma unroll
      for (int p=0;p<CD;p++) pp[p] += __shfl_xor(pp[p], lvl);
    if (lane < CO) {
      float* pr = &part[(wv*CO + lane)*CDP];
#pragma unroll
      for (int p4=0;p4<CD;p4+=4) {
        f32x4 w4 = { pp[p4], pp[p4+1], pp[p4+2], pp[p4+3] };
        *(f32x4*)(pr + p4) = w4;
      }
    }
    lds_barrier();
    // ---- cross-wave reduce + squash + publish
    if (tid < QN) {
      const int o2 = tid / CD, p2 = tid % CD;
      float s = 0.f;
#pragma unroll
      for (int w=0; w<NW; ++w) s += part[(w*CO+o2)*CDP + p2];
      float sq = s*s;
#pragma unroll
      for (int m=1;m<CD;m<<=1) sq += __shfl_xor(sq, m, CD);
      float f = (sq/(1.f+sq)) * rsqrtf(sq + 1e-9f);
      float vn = s * f;
      vb[(size_t)tt*QN + tid] = vn;
      float vn2 = __shfl_xor(vn, 1);
      if ((p2 & 1) == 0) {
        union { f16 h[2]; uint32_t w; } pk;
        pk.h[0] = (f16)vn; pk.h[1] = (f16)vn2;
        smat[o2*P2 + (p2>>1)] = pk.w;
      }
    }
    lds_barrier();
    // ---- broadcast v (packed f16)
#pragma unroll
    for (int q=0;q<CD/8;q++)
      vh.q4[q] = *(const uint4*)&smat[o*P2 + q*4];
  };

  loadu(Ua, 0);
  for (int t=0; t<T; t+=2) {
    loadu(Ub, (t+1 < T) ? t+1 : t);
    step(Ua, t);
    loadu(Ua, (t+2 < T) ? t+2 : t);
    step(Ub, t+1);
  }
}

// ---------------------------------------------------------------- final: LN512 -> length -> LN32
__global__ __launch_bounds__(512) void k_final(
    const float* __restrict__ v1,
    const float* __restrict__ g1, const float* __restrict__ b1,
    const float* __restrict__ g2, const float* __restrict__ b2,
    float* __restrict__ out)
{
  int bt = blockIdx.x;
  int tid = threadIdx.x;
  float x = v1[(size_t)bt*512 + tid];
  __shared__ float red[16];
  __shared__ float Ls[32];
  float s1 = x, s2 = x*x;
#pragma unroll
  for (int m=1;m<64;m<<=1){ s1 += __shfl_xor(s1,m,64); s2 += __shfl_xor(s2,m,64); }
  if ((tid & 63) == 0){ red[(tid>>6)*2] = s1; red[(tid>>6)*2+1] = s2; }
  __syncthreads();
  float S1 = 0.f, S2 = 0.f;
#pragma unroll
  for (int i=0;i<8;i++){ S1 += red[2*i]; S2 += red[2*i+1]; }
  float mean = S1/512.f, var = S2/512.f - mean*mean;
  float y = (x-mean)*rsqrtf(var+1e-3f)*g1[tid] + b1[tid];
  float ss = y*y;
  ss += __shfl_xor(ss,1,16); ss += __shfl_xor(ss,2,16);
  ss += __shfl_xor(ss,4,16); ss += __shfl_xor(ss,8,16);
  float L = sqrtf(ss + 1e-9f);
  if ((tid & 15) == 0) Ls[tid >> 4] = L;
  __syncthreads();
  if (tid < 32) {
    float l = Ls[tid];
    float t1 = l, t2 = l*l;
#pragma unroll
    for (int m=1;m<32;m<<=1){ t1 += __shfl_xor(t1,m,32); t2 += __shfl_xor(t2,m,32); }
    float mn = t1/32.f, vr = t2/32.f - mn*mn;
    out[(size_t)bt*32 + tid] = (l-mn)*rsqrtf(vr+1e-3f)*g2[tid] + b2[tid];
  }
}

// ---------------------------------------------------------------- workspace layout
static const size_t OFF_X1F   = 0;            // 20,971,520 B f16 [4,1024,40,64]
static const size_t OFF_WT16  = 20971520;     //     77,824 B f16 [64][600]
static const size_t OFF_X2    = 21049344;     // 10,485,760 B f32 [4,512,20,64]
static const size_t OFF_EMB0  = 31535104;     //    131,072 B f32 [4,512,16]
static const size_t OFF_UH0   = 31666176;     // 41,943,040 B f16 [4,512,1280,8]
static const size_t OFF_UH1   = 0;            // 167,772,160 B f16 [4,512,2560,16]
static const size_t OFF_EMBLN = 167772160;    //  1,048,576 B f32 (dead before scan0)
static const size_t OFF_V0    = 167772160;    //  1,048,576 B f32 (reuses EMBLN slot)
static const size_t OFF_V0LN  = 168820736;    //  1,048,576 B f32
static const size_t OFF_V1    = 169869312;    //  4,194,304 B f32 [4,512,32,16]
static const size_t WS_NEED   = 174063616;

extern "C" void kernel_launch(void* const* d_in, const int* in_sizes, int n_in,
                              void* d_out, int out_size, void* d_ws, size_t ws_size,
                              hipStream_t stream) {
  (void)in_sizes; (void)n_in; (void)out_size;
  if (ws_size < WS_NEED) return;

  const float* inputs = (const float*)d_in[0];
  const int*   lens   = (const int*)d_in[1];
  const float* c1w=(const float*)d_in[2],  *c1b=(const float*)d_in[3];
  const float* c2w=(const float*)d_in[4],  *c2b=(const float*)d_in[5];
  const float* pw =(const float*)d_in[6],  *pb =(const float*)d_in[7];
  const float* e0w=(const float*)d_in[8],  *e0b=(const float*)d_in[9];
  const float* e1w=(const float*)d_in[10], *e1b=(const float*)d_in[11];
  const float* lnig=(const float*)d_in[12],*lnib=(const float*)d_in[13];
  const float* W0=(const float*)d_in[14],  *B0=(const float*)d_in[15];
  const float* W1=(const float*)d_in[16],  *B1=(const float*)d_in[17];
  const float* lnm0g=(const float*)d_in[18],*lnm0b=(const float*)d_in[19];
  const float* lnm1g=(const float*)d_in[20],*lnm1b=(const float*)d_in[21];
  const float* lnog=(const float*)d_in[22], *lnob=(const float*)d_in[23];

  char* ws = (char*)d_ws;
  f16*   x1f   = (f16*)  (ws + OFF_X1F);
  f16*   wt16  = (f16*)  (ws + OFF_WT16);
  float* x2    = (float*)(ws + OFF_X2);
  float* emb0  = (float*)(ws + OFF_EMB0);
  f16*   uh0   = (f16*)  (ws + OFF_UH0);
  f16*   uh1   = (f16*)  (ws + OFF_UH1);
  float* embln = (float*)(ws + OFF_EMBLN);
  float* v0    = (float*)(ws + OFF_V0);
  float* v0ln  = (float*)(ws + OFF_V0LN);
  float* v1    = (float*)(ws + OFF_V1);

  k_conv1<<<40960, 256, 0, stream>>>(inputs, c1w, c1b, x1f);
  k_wcvt <<<152, 256, 0, stream>>>(c2w, wt16);
  k_conv2m<<<320, 256, 0, stream>>>(x1f, wt16, c2b, x2);
  k_proj <<<2048, 256, 0, stream>>>(x2, pw, pb, emb0);
  k_primary<<<2048, 128, 0, stream>>>(emb0, e0w, e0b, e1w, e1b, lnig, lnib, lens, embln);
  k_uhat<16,8><<<640, 256, 0, stream>>>(embln, W0, B0, uh0);
  k_scan3<16,8,40,false><<<4, 640, 0, stream>>>(uh0, v0, 512);
  k_ln128<<<2048, 128, 0, stream>>>(v0, lnm0g, lnm0b, v0ln);
  k_uhat<32,16><<<640, 256, 0, stream>>>(v0ln, W1, B1, uh1);
  k_scan3<32,16,32,true><<<4, 1024, 0, stream>>>(uh1, v1, 512);
  k_final<<<2048, 512, 0, stream>>>(v1, lnm1g, lnm1b, lnog, lnob, (float*)d_out);
}

// Round 5
// 2071.282 us; speedup vs baseline: 1.8595x; 1.4999x over previous
//
#include <hip/hip_runtime.h>
#include <hip/hip_fp16.h>

typedef _Float16 f16;
typedef _Float16 f16x2 __attribute__((ext_vector_type(2)));
typedef _Float16 f16x8 __attribute__((ext_vector_type(8)));
typedef float f32x4 __attribute__((ext_vector_type(4)));

#define DEV static __device__ __forceinline__

// LDS-only barrier — keeps global loads/stores in flight.
DEV void lds_barrier() {
  asm volatile("s_waitcnt lgkmcnt(0)" ::: "memory");
  __builtin_amdgcn_s_barrier();
  asm volatile("" ::: "memory");
}

// ---- VALU cross-lane reduction helpers (no DS pipe) ----
// DPP ctrl: quad_perm xor1=0xB1, xor2=0x4E, row_half_mirror=0x141, row_ror:N=0x120|N
template<int CTRL>
DEV float dpp_add(float x) {
  int y = __builtin_amdgcn_update_dpp(0, __builtin_bit_cast(int, x), CTRL, 0xf, 0xf, false);
  return x + __builtin_bit_cast(float, y);
}
template<int CTRL>
DEV float dpp_max(float x) {
  int y = __builtin_amdgcn_update_dpp(0, __builtin_bit_cast(int, x), CTRL, 0xf, 0xf, false);
  return fmaxf(x, __builtin_bit_cast(float, y));
}
template<int CTRL>
DEV float dpp_get(float x) {   // value from lane mapped by CTRL
  int y = __builtin_amdgcn_update_dpp(0, __builtin_bit_cast(int, x), CTRL, 0xf, 0xf, false);
  return __builtin_bit_cast(float, y);
}
DEV float pl32_add(float x) {  // x + x[lane^32]
  unsigned xi = __builtin_bit_cast(unsigned, x);
  auto r = __builtin_amdgcn_permlane32_swap(xi, xi, false, false);
  return __builtin_bit_cast(float, (unsigned)r[0]) + __builtin_bit_cast(float, (unsigned)r[1]);
}
DEV float pl32_max(float x) {
  unsigned xi = __builtin_bit_cast(unsigned, x);
  auto r = __builtin_amdgcn_permlane32_swap(xi, xi, false, false);
  return fmaxf(__builtin_bit_cast(float, (unsigned)r[0]),
               __builtin_bit_cast(float, (unsigned)r[1]));
}

// ---------------------------------------------------------------- conv1
__global__ __launch_bounds__(256) void k_conv1(
    const float* __restrict__ in, const float* __restrict__ w,
    const float* __restrict__ bias, f16* __restrict__ out)
{
  int idx = blockIdx.x*256 + threadIdx.x;
  int co = idx & 63;
  int ow = (idx >> 6) % 40;
  int oh = ((idx >> 6) / 40) % 1024;
  int b  = idx / (64*40*1024);
  float acc = bias[co];
#pragma unroll
  for (int kh=0; kh<3; kh++) {
    int ih = oh*2 + kh;
    if (ih >= 2048) continue;
#pragma unroll
    for (int kw=0; kw<3; kw++) {
      int iw = ow*2 + kw;
      if (iw >= 80) continue;
      acc += in[(b*2048 + ih)*80 + iw] * w[(kh*3+kw)*64 + co];
    }
  }
  out[idx] = (f16)fmaxf(acc, 0.f);
}

// ---------------------------------------------------------------- weight convert+transpose
__global__ __launch_bounds__(256) void k_wcvt(
    const float* __restrict__ w, f16* __restrict__ wt)
{
  int idx = blockIdx.x*256 + threadIdx.x;
  if (idx >= 38912) return;
  f16 v = (f16)0.f;
  if (idx < 38400) {
    int n = idx / 600, k = idx % 600;
    if (k < 576) v = (f16)w[k*64 + n];
  }
  wt[idx] = v;
}

// ---------------------------------------------------------------- conv2 as implicit GEMM (MFMA fp16)
__global__ __launch_bounds__(256) void k_conv2m(
    const f16* __restrict__ x1f, const f16* __restrict__ wt,
    const float* __restrict__ bias, float* __restrict__ out)
{
  __shared__ f16 Bt[38912];
  const int tid = threadIdx.x;
  for (int it = 0; it < 19; ++it) {
    const f16* g = wt + it*2048 + tid*8;
    f16* l = Bt + it*2048 + tid*8;
    __builtin_amdgcn_global_load_lds(
        (const __attribute__((address_space(1))) void*)g,
        (__attribute__((address_space(3))) void*)l, 16, 0, 0);
  }
  __syncthreads();

  const int wave = tid >> 6, l = tid & 63;
  const int lrow = l & 15, lk = l >> 4;
  const int m0 = blockIdx.x*128 + wave*32;

  const int mA = m0 + lrow, mB = m0 + 16 + lrow;
  int bA = mA/10240, rA = mA%10240, ohA = rA/20, owA = rA%20;
  int bB = mB/10240, rB = mB%10240, ohB = rB/20, owB = rB%20;
  const f16* pA = x1f + ((size_t)((bA*1024 + ohA*2)*40 + owA*2))*64;
  const f16* pB = x1f + ((size_t)((bB*1024 + ohB*2)*40 + owB*2))*64;

  f32x4 acc[2][4];
#pragma unroll
  for (int i=0;i<2;i++)
#pragma unroll
    for (int j=0;j<4;j++) acc[i][j] = (f32x4){0.f,0.f,0.f,0.f};

  const f16x8 zero8 = {};
#pragma unroll
  for (int kk=0; kk<18; ++kk) {
    const int tap = kk >> 1;
    const int kh = tap/3, kw = tap%3;
    const int ci0 = ((kk&1)<<5) + lk*8;
    const int off = (kh*40 + kw)*64 + ci0;
    const bool okA = (ohA*2+kh < 1024) && (owA*2+kw < 40);
    const bool okB = (ohB*2+kh < 1024) && (owB*2+kw < 40);
    f16x8 a0 = okA ? *(const f16x8*)(pA + off) : zero8;
    f16x8 a1 = okB ? *(const f16x8*)(pB + off) : zero8;
#pragma unroll
    for (int nf=0; nf<4; ++nf) {
      f16x8 bb = *(const f16x8*)&Bt[(nf*16 + lrow)*600 + kk*32 + lk*8];
      acc[0][nf] = __builtin_amdgcn_mfma_f32_16x16x32_f16(a0, bb, acc[0][nf], 0,0,0);
      acc[1][nf] = __builtin_amdgcn_mfma_f32_16x16x32_f16(a1, bb, acc[1][nf], 0,0,0);
    }
  }
#pragma unroll
  for (int nf=0; nf<4; ++nf) {
    const int n = nf*16 + lrow;
    const float bi = bias[n];
#pragma unroll
    for (int mf=0; mf<2; ++mf)
#pragma unroll
      for (int r=0; r<4; ++r) {
        int mrow = m0 + mf*16 + lk*4 + r;
        out[(size_t)mrow*64 + n] = fmaxf(acc[mf][nf][r] + bi, 0.f);
      }
  }
}

// ---------------------------------------------------------------- proj
__global__ __launch_bounds__(256) void k_proj(
    const float* __restrict__ x, const float* __restrict__ pw,
    const float* __restrict__ pb, float* __restrict__ out)
{
  int bt = blockIdx.x;
  int tid = threadIdx.x;
  int j = tid >> 4;
  int l = tid & 15;
  const float* xr = x + (size_t)bt*1280;
  float s = 0.f;
  for (int k=0; k<80; k++) {
    int f = l + 16*k;
    s += xr[f] * pw[f*16 + j];
  }
  s += __shfl_xor(s, 1, 16); s += __shfl_xor(s, 2, 16);
  s += __shfl_xor(s, 4, 16); s += __shfl_xor(s, 8, 16);
  if (l == 0) out[bt*16 + j] = s + pb[j];
}

// ------------------------------------------- primary caps
__global__ __launch_bounds__(128) void k_primary(
    const float* __restrict__ emb0,
    const float* __restrict__ w0, const float* __restrict__ b0,
    const float* __restrict__ w1, const float* __restrict__ b1,
    const float* __restrict__ g, const float* __restrict__ be,
    const int* __restrict__ lens, float* __restrict__ out)
{
  int bt = blockIdx.x;
  int b = bt >> 9, t = bt & 511;
  int tid = threadIdx.x;
  int c = tid & 7, j = tid >> 3;
  __shared__ float rows[3][16];
  __shared__ float red[4];
  if (tid < 48) {
    int kh = tid / 16, jj = tid % 16;
    int ts = t + kh - 1;
    rows[kh][jj] = (ts >= 0 && ts < 512) ? emb0[(b*512+ts)*16 + jj] : 0.f;
  }
  __syncthreads();
  float a0 = b0[c], a1 = b1[c];
#pragma unroll
  for (int kh=0; kh<3; kh++)
#pragma unroll
    for (int kw=0; kw<3; kw++) {
      int jj = j + kw - 1;
      if (jj < 0 || jj >= 16) continue;
      float xv = rows[kh][jj];
      a0 += xv * w0[(kh*3+kw)*8 + c];
      a1 += xv * w1[(kh*3+kw)*8 + c];
    }
  float e = fmaxf(a0, a1);
  int valid = (lens[b] + 3) >> 2;
  if (t >= valid) e = 0.f;
  float sq = e*e;
  sq += __shfl_xor(sq, 1, 8); sq += __shfl_xor(sq, 2, 8); sq += __shfl_xor(sq, 4, 8);
  float val = e * (sq / (1.f + sq)) * rsqrtf(sq + 1e-9f);
  float s1 = val, s2 = val*val;
#pragma unroll
  for (int m=1;m<64;m<<=1){ s1 += __shfl_xor(s1,m,64); s2 += __shfl_xor(s2,m,64); }
  if ((tid & 63) == 0){ red[(tid>>6)*2] = s1; red[(tid>>6)*2+1] = s2; }
  __syncthreads();
  float S1 = red[0]+red[2], S2 = red[1]+red[3];
  float mean = S1/128.f;
  float var  = S2/128.f - mean*mean;
  out[(size_t)bt*128 + tid] = (val-mean)*rsqrtf(var+1e-3f)*g[tid] + be[tid];
}

// ---------------------------------------------------------------- generic LN over 128
__global__ __launch_bounds__(128) void k_ln128(
    const float* __restrict__ in, const float* __restrict__ g,
    const float* __restrict__ be, float* __restrict__ out)
{
  int bt = blockIdx.x, tid = threadIdx.x;
  float x = in[(size_t)bt*128 + tid];
  __shared__ float red[4];
  float s1 = x, s2 = x*x;
#pragma unroll
  for (int m=1;m<64;m<<=1){ s1 += __shfl_xor(s1,m,64); s2 += __shfl_xor(s2,m,64); }
  if ((tid & 63) == 0){ red[(tid>>6)*2] = s1; red[(tid>>6)*2+1] = s2; }
  __syncthreads();
  float S1 = red[0]+red[2], S2 = red[1]+red[3];
  float mean = S1/128.f;
  float var  = S2/128.f - mean*mean;
  out[(size_t)bt*128 + tid] = (x-mean)*rsqrtf(var+1e-3f)*g[tid] + be[tid];
}

// ---------------------------------------------------------------- u_hat precompute
template<int CO, int CD>
__global__ __launch_bounds__(256) void k_uhat(
    const float* __restrict__ src, const float* __restrict__ W,
    const float* __restrict__ Bs, f16* __restrict__ out)
{
  constexpr int NP = 80*CO;
  int wid = __builtin_amdgcn_readfirstlane(blockIdx.x*4 + (threadIdx.x >> 6));
  int lane = threadIdx.x & 63;
  int n   = wid % 80;
  int btc = wid / 80;
  int bt = btc*64 + lane;
  int b = bt >> 9, t = bt & 511;
  int k = n >> 4, i = n & 15;
  int ts = t + k - 2;
  float x[8];
  if (ts >= 0 && ts < 512) {
    const float* xr = src + ((size_t)(b*512+ts)*16 + i)*8;
    f32x4 x0 = *(const f32x4*)xr;
    f32x4 x1 = *(const f32x4*)(xr+4);
#pragma unroll
    for (int q=0;q<4;q++){ x[q]=x0[q]; x[4+q]=x1[q]; }
  } else {
#pragma unroll
    for (int q=0;q<8;q++) x[q]=0.f;
  }
  const float* Wn = W  + (size_t)n*CO*CD*8;
  const float* Bn = Bs + (size_t)n*CO*CD;
  for (int o=0; o<CO; o++) {
    alignas(16) f16 res[CD];
#pragma unroll
    for (int p=0;p<CD;p++) {
      float a = Bn[o*CD+p];
#pragma unroll
      for (int q=0;q<8;q++) a += Wn[(o*CD+p)*8+q]*x[q];
      res[p] = (f16)a;
    }
    f16* op = out + ((size_t)bt*NP + (size_t)n*CO + o)*CD;
    *(uint4*)op = *(const uint4*)res;
    if constexpr (CD==16) *((uint4*)op+1) = *((const uint4*)res+1);
  }
}

// ---------------------------------------------------------------- routing scan v4
// 8 waves/batch-block. Lane bits: o_lo = lane[0:3]; CO=32 adds o_hi = lane[5];
// jj = remaining bits + wave. Each lane = unique (o, jj) -> no in-wave n-reduce.
// All softmax/squash reductions on VALU (DPP ror / quad_perm / permlane32_swap).
// v kept packed f16; logits via v_dot2_f32_f16.
template<int CO, int CD, int NW, bool MASK>
__global__ __launch_bounds__(NW*64, 1) void k_scan4(
    const f16* __restrict__ uh, float* __restrict__ vseq, int T)
{
  constexpr int TH = NW*64;
  constexpr int JPW = 64/CO;                 // jj groups per wave (2 or 4)
  constexpr int NJ  = NW*JPW;                // 16 (L1) or 32 (L0)
  constexpr int SLOTS = (80 + NJ - 1)/NJ;    // 5 (L1) or 3 (L0)
  constexpr int NP = 80*CO;
  constexpr int QN = CO*CD;                  // 512 (L1) / 128 (L0)
  constexpr int P2 = CD/2;                   // smat row stride in u32

  __shared__ float    part[NJ*CO*CD];
  __shared__ unsigned smat[CO*P2];

  const int b = blockIdx.x;
  const int tid = threadIdx.x;
  const int wv = tid >> 6, lane = tid & 63;
  const int o  = (CO==32) ? ((lane & 15) | (((lane>>5)&1)<<4)) : (lane & 15);
  const int jw = (CO==32) ? ((lane>>4)&1) : (lane>>4);
  const int jj = jw + JPW*wv;

  const f16* __restrict__ ub = uh + (size_t)b*T*NP*CD;
  float* __restrict__ vb = vseq + (size_t)b*T*QN;

  unsigned uoff[SLOTS];
  bool valid[SLOTS];
#pragma unroll
  for (int s=0;s<SLOTS;s++) {
    int n = jj + NJ*s;
    valid[s] = (n < 80);
    if (n >= 80) n = jj;
    uoff[s] = (unsigned)(n*CO + o)*CD;
  }

  union VH { unsigned w[P2]; f16x2 h2[P2]; uint4 q4[CD/8]; } vh;
#pragma unroll
  for (int q=0;q<P2;q++) vh.w[q] = 0u;

  f16x8 Ua[SLOTS][CD/8], Ub[SLOTS][CD/8];

  auto loadu = [&](f16x8 (&U)[SLOTS][CD/8], int tt) {
    const f16* base = ub + (size_t)tt*NP*CD;
#pragma unroll
    for (int s=0;s<SLOTS;s++)
#pragma unroll
      for (int q=0;q<CD/8;q++)
        U[s][q] = *(const f16x8*)(base + uoff[s] + q*8);
  };

  auto step = [&](const f16x8 (&U)[SLOTS][CD/8], int tt) {
    // ---- logits via dot2 (f32 accum)
    float lg[SLOTS];
#pragma unroll
    for (int s=0;s<SLOTS;s++) {
      float a = 0.f;
#pragma unroll
      for (int q=0;q<CD/8;q++) {
        const f16x2* u2 = (const f16x2*)&U[s][q];
#pragma unroll
        for (int z=0;z<4;z++)
          a = __builtin_amdgcn_fdot2(u2[z], vh.h2[q*4+z], a, false);
      }
      if (MASK && o == 0) a -= 1e9f;
      lg[s] = a;
    }
    // ---- softmax over o: VALU-only reductions, slots interleaved
    float mx[SLOTS], ex[SLOTS], sm[SLOTS];
#pragma unroll
    for (int s=0;s<SLOTS;s++) mx[s] = lg[s];
#pragma unroll
    for (int s=0;s<SLOTS;s++) mx[s] = dpp_max<0x121>(mx[s]);
#pragma unroll
    for (int s=0;s<SLOTS;s++) mx[s] = dpp_max<0x122>(mx[s]);
#pragma unroll
    for (int s=0;s<SLOTS;s++) mx[s] = dpp_max<0x124>(mx[s]);
#pragma unroll
    for (int s=0;s<SLOTS;s++) mx[s] = dpp_max<0x128>(mx[s]);
    if (CO == 32) {
#pragma unroll
      for (int s=0;s<SLOTS;s++) mx[s] = pl32_max(mx[s]);
    }
#pragma unroll
    for (int s=0;s<SLOTS;s++) { ex[s] = __expf(lg[s]-mx[s]); sm[s] = ex[s]; }
#pragma unroll
    for (int s=0;s<SLOTS;s++) sm[s] = dpp_add<0x121>(sm[s]);
#pragma unroll
    for (int s=0;s<SLOTS;s++) sm[s] = dpp_add<0x122>(sm[s]);
#pragma unroll
    for (int s=0;s<SLOTS;s++) sm[s] = dpp_add<0x124>(sm[s]);
#pragma unroll
    for (int s=0;s<SLOTS;s++) sm[s] = dpp_add<0x128>(sm[s]);
    if (CO == 32) {
#pragma unroll
      for (int s=0;s<SLOTS;s++) sm[s] = pl32_add(sm[s]);
    }
    // ---- PV partial (per-lane, unique (o,jj))
    float pp[CD];
#pragma unroll
    for (int p=0;p<CD;p++) pp[p] = 0.f;
#pragma unroll
    for (int s=0;s<SLOTS;s++) {
      float c = ex[s] * __builtin_amdgcn_rcpf(sm[s]);
      if (!valid[s]) c = 0.f;
#pragma unroll
      for (int p=0;p<CD;p++) pp[p] += c * (float)U[s][p/8][p&7];
    }
    float* pr = &part[(jj*CO + o)*CD];
#pragma unroll
    for (int p=0;p<CD;p+=4) {
      f32x4 w4 = { pp[p], pp[p+1], pp[p+2], pp[p+3] };
      *(f32x4*)(pr + p) = w4;
    }
    lds_barrier();
    // ---- cross-row reduce + squash + publish (first QN threads, whole waves)
    if (QN == TH || tid < QN) {
      const int p2 = tid & (CD-1), o2 = tid >> (CD==16 ? 4 : 3);
      float sv = 0.f;
#pragma unroll
      for (int r=0;r<NJ;r++) sv += part[(r*CO + o2)*CD + p2];
      float sq = sv*sv;
      if (CD == 16) {
        sq = dpp_add<0x121>(sq); sq = dpp_add<0x122>(sq);
        sq = dpp_add<0x124>(sq); sq = dpp_add<0x128>(sq);
      } else {
        sq = dpp_add<0xB1>(sq); sq = dpp_add<0x4E>(sq); sq = dpp_add<0x141>(sq);
      }
      float f = sq * __builtin_amdgcn_rcpf(1.f + sq) * rsqrtf(sq + 1e-9f);
      float vn = sv * f;
      vb[(size_t)tt*QN + tid] = vn;
      float vn1 = dpp_get<0xB1>(vn);          // value from lane^1
      if ((p2 & 1) == 0) {
        union { f16x2 h2; unsigned w; } pk;
        pk.h2 = (f16x2){ (f16)vn, (f16)vn1 };
        smat[o2*P2 + (p2>>1)] = pk.w;
      }
    }
    lds_barrier();
#pragma unroll
    for (int q=0;q<CD/8;q++)
      vh.q4[q] = *(const uint4*)&smat[o*P2 + q*4];
  };

  loadu(Ua, 0);
  for (int t=0; t<T; t+=2) {
    loadu(Ub, (t+1 < T) ? t+1 : t);
    step(Ua, t);
    loadu(Ua, (t+2 < T) ? t+2 : t);
    step(Ub, t+1);
  }
}

// ---------------------------------------------------------------- final: LN512 -> length -> LN32
__global__ __launch_bounds__(512) void k_final(
    const float* __restrict__ v1,
    const float* __restrict__ g1, const float* __restrict__ b1,
    const float* __restrict__ g2, const float* __restrict__ b2,
    float* __restrict__ out)
{
  int bt = blockIdx.x;
  int tid = threadIdx.x;
  float x = v1[(size_t)bt*512 + tid];
  __shared__ float red[16];
  __shared__ float Ls[32];
  float s1 = x, s2 = x*x;
#pragma unroll
  for (int m=1;m<64;m<<=1){ s1 += __shfl_xor(s1,m,64); s2 += __shfl_xor(s2,m,64); }
  if ((tid & 63) == 0){ red[(tid>>6)*2] = s1; red[(tid>>6)*2+1] = s2; }
  __syncthreads();
  float S1 = 0.f, S2 = 0.f;
#pragma unroll
  for (int i=0;i<8;i++){ S1 += red[2*i]; S2 += red[2*i+1]; }
  float mean = S1/512.f, var = S2/512.f - mean*mean;
  float y = (x-mean)*rsqrtf(var+1e-3f)*g1[tid] + b1[tid];
  float ss = y*y;
  ss += __shfl_xor(ss,1,16); ss += __shfl_xor(ss,2,16);
  ss += __shfl_xor(ss,4,16); ss += __shfl_xor(ss,8,16);
  float L = sqrtf(ss + 1e-9f);
  if ((tid & 15) == 0) Ls[tid >> 4] = L;
  __syncthreads();
  if (tid < 32) {
    float l = Ls[tid];
    float t1 = l, t2 = l*l;
#pragma unroll
    for (int m=1;m<32;m<<=1){ t1 += __shfl_xor(t1,m,32); t2 += __shfl_xor(t2,m,32); }
    float mn = t1/32.f, vr = t2/32.f - mn*mn;
    out[(size_t)bt*32 + tid] = (l-mn)*rsqrtf(vr+1e-3f)*g2[tid] + b2[tid];
  }
}

// ---------------------------------------------------------------- workspace layout
static const size_t OFF_X1F   = 0;            // 20,971,520 B f16 [4,1024,40,64]
static const size_t OFF_WT16  = 20971520;     //     77,824 B f16 [64][600]
static const size_t OFF_X2    = 21049344;     // 10,485,760 B f32 [4,512,20,64]
static const size_t OFF_EMB0  = 31535104;     //    131,072 B f32 [4,512,16]
static const size_t OFF_UH0   = 31666176;     // 41,943,040 B f16 [4,512,1280,8]
static const size_t OFF_UH1   = 0;            // 167,772,160 B f16 [4,512,2560,16]
static const size_t OFF_EMBLN = 167772160;    //  1,048,576 B f32 (dead before scan0)
static const size_t OFF_V0    = 167772160;    //  1,048,576 B f32 (reuses EMBLN slot)
static const size_t OFF_V0LN  = 168820736;    //  1,048,576 B f32
static const size_t OFF_V1    = 169869312;    //  4,194,304 B f32 [4,512,32,16]
static const size_t WS_NEED   = 174063616;

extern "C" void kernel_launch(void* const* d_in, const int* in_sizes, int n_in,
                              void* d_out, int out_size, void* d_ws, size_t ws_size,
                              hipStream_t stream) {
  (void)in_sizes; (void)n_in; (void)out_size;
  if (ws_size < WS_NEED) return;

  const float* inputs = (const float*)d_in[0];
  const int*   lens   = (const int*)d_in[1];
  const float* c1w=(const float*)d_in[2],  *c1b=(const float*)d_in[3];
  const float* c2w=(const float*)d_in[4],  *c2b=(const float*)d_in[5];
  const float* pw =(const float*)d_in[6],  *pb =(const float*)d_in[7];
  const float* e0w=(const float*)d_in[8],  *e0b=(const float*)d_in[9];
  const float* e1w=(const float*)d_in[10], *e1b=(const float*)d_in[11];
  const float* lnig=(const float*)d_in[12],*lnib=(const float*)d_in[13];
  const float* W0=(const float*)d_in[14],  *B0=(const float*)d_in[15];
  const float* W1=(const float*)d_in[16],  *B1=(const float*)d_in[17];
  const float* lnm0g=(const float*)d_in[18],*lnm0b=(const float*)d_in[19];
  const float* lnm1g=(const float*)d_in[20],*lnm1b=(const float*)d_in[21];
  const float* lnog=(const float*)d_in[22], *lnob=(const float*)d_in[23];

  char* ws = (char*)d_ws;
  f16*   x1f   = (f16*)  (ws + OFF_X1F);
  f16*   wt16  = (f16*)  (ws + OFF_WT16);
  float* x2    = (float*)(ws + OFF_X2);
  float* emb0  = (float*)(ws + OFF_EMB0);
  f16*   uh0   = (f16*)  (ws + OFF_UH0);
  f16*   uh1   = (f16*)  (ws + OFF_UH1);
  float* embln = (float*)(ws + OFF_EMBLN);
  float* v0    = (float*)(ws + OFF_V0);
  float* v0ln  = (float*)(ws + OFF_V0LN);
  float* v1    = (float*)(ws + OFF_V1);

  k_conv1<<<40960, 256, 0, stream>>>(inputs, c1w, c1b, x1f);
  k_wcvt <<<152, 256, 0, stream>>>(c2w, wt16);
  k_conv2m<<<320, 256, 0, stream>>>(x1f, wt16, c2b, x2);
  k_proj <<<2048, 256, 0, stream>>>(x2, pw, pb, emb0);
  k_primary<<<2048, 128, 0, stream>>>(emb0, e0w, e0b, e1w, e1b, lnig, lnib, lens, embln);
  k_uhat<16,8><<<640, 256, 0, stream>>>(embln, W0, B0, uh0);
  k_scan4<16,8,8,false><<<4, 512, 0, stream>>>(uh0, v0, 512);
  k_ln128<<<2048, 128, 0, stream>>>(v0, lnm0g, lnm0b, v0ln);
  k_uhat<32,16><<<640, 256, 0, stream>>>(v0ln, W1, B1, uh1);
  k_scan4<32,16,8,true><<<4, 512, 0, stream>>>(uh1, v1, 512);
  k_final<<<2048, 512, 0, stream>>>(v1, lnm1g, lnm1b, lnog, lnob, (float*)d_out);
}

// Round 6
// 2043.394 us; speedup vs baseline: 1.8848x; 1.0136x over previous
//
#include <hip/hip_runtime.h>
#include <hip/hip_fp16.h>

typedef _Float16 f16;
typedef _Float16 f16x2 __attribute__((ext_vector_type(2)));
typedef _Float16 f16x8 __attribute__((ext_vector_type(8)));
typedef float f32x4 __attribute__((ext_vector_type(4)));

#define DEV static __device__ __forceinline__

// LDS-only barrier — keeps global loads/stores in flight.
DEV void lds_barrier() {
  asm volatile("s_waitcnt lgkmcnt(0)" ::: "memory");
  __builtin_amdgcn_s_barrier();
  asm volatile("" ::: "memory");
}

// ---- VALU cross-lane reduction helpers (no DS pipe) ----
template<int CTRL>
DEV float dpp_add(float x) {
  int y = __builtin_amdgcn_update_dpp(0, __builtin_bit_cast(int, x), CTRL, 0xf, 0xf, false);
  return x + __builtin_bit_cast(float, y);
}
template<int CTRL>
DEV float dpp_max(float x) {
  int y = __builtin_amdgcn_update_dpp(0, __builtin_bit_cast(int, x), CTRL, 0xf, 0xf, false);
  return fmaxf(x, __builtin_bit_cast(float, y));
}
template<int CTRL>
DEV float dpp_get(float x) {
  int y = __builtin_amdgcn_update_dpp(0, __builtin_bit_cast(int, x), CTRL, 0xf, 0xf, false);
  return __builtin_bit_cast(float, y);
}
DEV float pl32_add(float x) {  // x + x[lane^32]
  unsigned xi = __builtin_bit_cast(unsigned, x);
  auto r = __builtin_amdgcn_permlane32_swap(xi, xi, false, false);
  return __builtin_bit_cast(float, (unsigned)r[0]) + __builtin_bit_cast(float, (unsigned)r[1]);
}
DEV float pl32_max(float x) {
  unsigned xi = __builtin_bit_cast(unsigned, x);
  auto r = __builtin_amdgcn_permlane32_swap(xi, xi, false, false);
  return fmaxf(__builtin_bit_cast(float, (unsigned)r[0]),
               __builtin_bit_cast(float, (unsigned)r[1]));
}
DEV float swap16_add(float x) {  // x + x[lane^16]
#if __has_builtin(__builtin_amdgcn_permlane16_swap)
  unsigned xi = __builtin_bit_cast(unsigned, x);
  auto r = __builtin_amdgcn_permlane16_swap(xi, xi, false, false);
  return __builtin_bit_cast(float, (unsigned)r[0]) + __builtin_bit_cast(float, (unsigned)r[1]);
#else
  int y = __builtin_amdgcn_ds_swizzle(__builtin_bit_cast(int, x), 0x401F);
  return x + __builtin_bit_cast(float, y);
#endif
}

// ---------------------------------------------------------------- conv1
__global__ __launch_bounds__(256) void k_conv1(
    const float* __restrict__ in, const float* __restrict__ w,
    const float* __restrict__ bias, f16* __restrict__ out)
{
  int idx = blockIdx.x*256 + threadIdx.x;
  int co = idx & 63;
  int ow = (idx >> 6) % 40;
  int oh = ((idx >> 6) / 40) % 1024;
  int b  = idx / (64*40*1024);
  float acc = bias[co];
#pragma unroll
  for (int kh=0; kh<3; kh++) {
    int ih = oh*2 + kh;
    if (ih >= 2048) continue;
#pragma unroll
    for (int kw=0; kw<3; kw++) {
      int iw = ow*2 + kw;
      if (iw >= 80) continue;
      acc += in[(b*2048 + ih)*80 + iw] * w[(kh*3+kw)*64 + co];
    }
  }
  out[idx] = (f16)fmaxf(acc, 0.f);
}

// ---------------------------------------------------------------- weight convert+transpose
__global__ __launch_bounds__(256) void k_wcvt(
    const float* __restrict__ w, f16* __restrict__ wt)
{
  int idx = blockIdx.x*256 + threadIdx.x;
  if (idx >= 38912) return;
  f16 v = (f16)0.f;
  if (idx < 38400) {
    int n = idx / 600, k = idx % 600;
    if (k < 576) v = (f16)w[k*64 + n];
  }
  wt[idx] = v;
}

// ---------------------------------------------------------------- conv2 as implicit GEMM (MFMA fp16)
__global__ __launch_bounds__(256) void k_conv2m(
    const f16* __restrict__ x1f, const f16* __restrict__ wt,
    const float* __restrict__ bias, float* __restrict__ out)
{
  __shared__ f16 Bt[38912];
  const int tid = threadIdx.x;
  for (int it = 0; it < 19; ++it) {
    const f16* g = wt + it*2048 + tid*8;
    f16* l = Bt + it*2048 + tid*8;
    __builtin_amdgcn_global_load_lds(
        (const __attribute__((address_space(1))) void*)g,
        (__attribute__((address_space(3))) void*)l, 16, 0, 0);
  }
  __syncthreads();

  const int wave = tid >> 6, l = tid & 63;
  const int lrow = l & 15, lk = l >> 4;
  const int m0 = blockIdx.x*128 + wave*32;

  const int mA = m0 + lrow, mB = m0 + 16 + lrow;
  int bA = mA/10240, rA = mA%10240, ohA = rA/20, owA = rA%20;
  int bB = mB/10240, rB = mB%10240, ohB = rB/20, owB = rB%20;
  const f16* pA = x1f + ((size_t)((bA*1024 + ohA*2)*40 + owA*2))*64;
  const f16* pB = x1f + ((size_t)((bB*1024 + ohB*2)*40 + owB*2))*64;

  f32x4 acc[2][4];
#pragma unroll
  for (int i=0;i<2;i++)
#pragma unroll
    for (int j=0;j<4;j++) acc[i][j] = (f32x4){0.f,0.f,0.f,0.f};

  const f16x8 zero8 = {};
#pragma unroll
  for (int kk=0; kk<18; ++kk) {
    const int tap = kk >> 1;
    const int kh = tap/3, kw = tap%3;
    const int ci0 = ((kk&1)<<5) + lk*8;
    const int off = (kh*40 + kw)*64 + ci0;
    const bool okA = (ohA*2+kh < 1024) && (owA*2+kw < 40);
    const bool okB = (ohB*2+kh < 1024) && (owB*2+kw < 40);
    f16x8 a0 = okA ? *(const f16x8*)(pA + off) : zero8;
    f16x8 a1 = okB ? *(const f16x8*)(pB + off) : zero8;
#pragma unroll
    for (int nf=0; nf<4; ++nf) {
      f16x8 bb = *(const f16x8*)&Bt[(nf*16 + lrow)*600 + kk*32 + lk*8];
      acc[0][nf] = __builtin_amdgcn_mfma_f32_16x16x32_f16(a0, bb, acc[0][nf], 0,0,0);
      acc[1][nf] = __builtin_amdgcn_mfma_f32_16x16x32_f16(a1, bb, acc[1][nf], 0,0,0);
    }
  }
#pragma unroll
  for (int nf=0; nf<4; ++nf) {
    const int n = nf*16 + lrow;
    const float bi = bias[n];
#pragma unroll
    for (int mf=0; mf<2; ++mf)
#pragma unroll
      for (int r=0; r<4; ++r) {
        int mrow = m0 + mf*16 + lk*4 + r;
        out[(size_t)mrow*64 + n] = fmaxf(acc[mf][nf][r] + bi, 0.f);
      }
  }
}

// ---------------------------------------------------------------- proj
__global__ __launch_bounds__(256) void k_proj(
    const float* __restrict__ x, const float* __restrict__ pw,
    const float* __restrict__ pb, float* __restrict__ out)
{
  int bt = blockIdx.x;
  int tid = threadIdx.x;
  int j = tid >> 4;
  int l = tid & 15;
  const float* xr = x + (size_t)bt*1280;
  float s = 0.f;
  for (int k=0; k<80; k++) {
    int f = l + 16*k;
    s += xr[f] * pw[f*16 + j];
  }
  s += __shfl_xor(s, 1, 16); s += __shfl_xor(s, 2, 16);
  s += __shfl_xor(s, 4, 16); s += __shfl_xor(s, 8, 16);
  if (l == 0) out[bt*16 + j] = s + pb[j];
}

// ------------------------------------------- primary caps
__global__ __launch_bounds__(128) void k_primary(
    const float* __restrict__ emb0,
    const float* __restrict__ w0, const float* __restrict__ b0,
    const float* __restrict__ w1, const float* __restrict__ b1,
    const float* __restrict__ g, const float* __restrict__ be,
    const int* __restrict__ lens, float* __restrict__ out)
{
  int bt = blockIdx.x;
  int b = bt >> 9, t = bt & 511;
  int tid = threadIdx.x;
  int c = tid & 7, j = tid >> 3;
  __shared__ float rows[3][16];
  __shared__ float red[4];
  if (tid < 48) {
    int kh = tid / 16, jj = tid % 16;
    int ts = t + kh - 1;
    rows[kh][jj] = (ts >= 0 && ts < 512) ? emb0[(b*512+ts)*16 + jj] : 0.f;
  }
  __syncthreads();
  float a0 = b0[c], a1 = b1[c];
#pragma unroll
  for (int kh=0; kh<3; kh++)
#pragma unroll
    for (int kw=0; kw<3; kw++) {
      int jj = j + kw - 1;
      if (jj < 0 || jj >= 16) continue;
      float xv = rows[kh][jj];
      a0 += xv * w0[(kh*3+kw)*8 + c];
      a1 += xv * w1[(kh*3+kw)*8 + c];
    }
  float e = fmaxf(a0, a1);
  int valid = (lens[b] + 3) >> 2;
  if (t >= valid) e = 0.f;
  float sq = e*e;
  sq += __shfl_xor(sq, 1, 8); sq += __shfl_xor(sq, 2, 8); sq += __shfl_xor(sq, 4, 8);
  float val = e * (sq / (1.f + sq)) * rsqrtf(sq + 1e-9f);
  float s1 = val, s2 = val*val;
#pragma unroll
  for (int m=1;m<64;m<<=1){ s1 += __shfl_xor(s1,m,64); s2 += __shfl_xor(s2,m,64); }
  if ((tid & 63) == 0){ red[(tid>>6)*2] = s1; red[(tid>>6)*2+1] = s2; }
  __syncthreads();
  float S1 = red[0]+red[2], S2 = red[1]+red[3];
  float mean = S1/128.f;
  float var  = S2/128.f - mean*mean;
  out[(size_t)bt*128 + tid] = (val-mean)*rsqrtf(var+1e-3f)*g[tid] + be[tid];
}

// ---------------------------------------------------------------- generic LN over 128
__global__ __launch_bounds__(128) void k_ln128(
    const float* __restrict__ in, const float* __restrict__ g,
    const float* __restrict__ be, float* __restrict__ out)
{
  int bt = blockIdx.x, tid = threadIdx.x;
  float x = in[(size_t)bt*128 + tid];
  __shared__ float red[4];
  float s1 = x, s2 = x*x;
#pragma unroll
  for (int m=1;m<64;m<<=1){ s1 += __shfl_xor(s1,m,64); s2 += __shfl_xor(s2,m,64); }
  if ((tid & 63) == 0){ red[(tid>>6)*2] = s1; red[(tid>>6)*2+1] = s2; }
  __syncthreads();
  float S1 = red[0]+red[2], S2 = red[1]+red[3];
  float mean = S1/128.f;
  float var  = S2/128.f - mean*mean;
  out[(size_t)bt*128 + tid] = (x-mean)*rsqrtf(var+1e-3f)*g[tid] + be[tid];
}

// ---------------------------------------------------------------- u_hat precompute
template<int CO, int CD>
__global__ __launch_bounds__(256) void k_uhat(
    const float* __restrict__ src, const float* __restrict__ W,
    const float* __restrict__ Bs, f16* __restrict__ out)
{
  constexpr int NP = 80*CO;
  int wid = __builtin_amdgcn_readfirstlane(blockIdx.x*4 + (threadIdx.x >> 6));
  int lane = threadIdx.x & 63;
  int n   = wid % 80;
  int btc = wid / 80;
  int bt = btc*64 + lane;
  int b = bt >> 9, t = bt & 511;
  int k = n >> 4, i = n & 15;
  int ts = t + k - 2;
  float x[8];
  if (ts >= 0 && ts < 512) {
    const float* xr = src + ((size_t)(b*512+ts)*16 + i)*8;
    f32x4 x0 = *(const f32x4*)xr;
    f32x4 x1 = *(const f32x4*)(xr+4);
#pragma unroll
    for (int q=0;q<4;q++){ x[q]=x0[q]; x[4+q]=x1[q]; }
  } else {
#pragma unroll
    for (int q=0;q<8;q++) x[q]=0.f;
  }
  const float* Wn = W  + (size_t)n*CO*CD*8;
  const float* Bn = Bs + (size_t)n*CO*CD;
  for (int o=0; o<CO; o++) {
    alignas(16) f16 res[CD];
#pragma unroll
    for (int p=0;p<CD;p++) {
      float a = Bn[o*CD+p];
#pragma unroll
      for (int q=0;q<8;q++) a += Wn[(o*CD+p)*8+q]*x[q];
      res[p] = (f16)a;
    }
    f16* op = out + ((size_t)bt*NP + (size_t)n*CO + o)*CD;
    *(uint4*)op = *(const uint4*)res;
    if constexpr (CD==16) *((uint4*)op+1) = *((const uint4*)res+1);
  }
}

// ---------------------------------------------------------------- routing scan v5
// 8 waves/batch-block. Lane bits: o = lane[0:3](+lane[5] for CO=32); jw = rest.
// Softmax/squash on VALU (DPP + permlane32_swap). jw-partials reduced IN-REGISTER
// (permlane16/32_swap) before LDS -> part has only NW rows; padded strides kill
// bank conflicts (write starts spread over 8 banks; reads <=2-way).
template<int CO, int CD, int NW, bool MASK>
__global__ __launch_bounds__(NW*64, 1) void k_scan5(
    const f16* __restrict__ uh, float* __restrict__ vseq, int T)
{
  constexpr int TH = NW*64;
  constexpr int JPW = 64/CO;                 // jj groups per wave (2 or 4)
  constexpr int NJ  = NW*JPW;                // 16 (L1) or 32 (L0)
  constexpr int SLOTS = (80 + NJ - 1)/NJ;    // 5 (L1) or 3 (L0)
  constexpr int NP = 80*CO;
  constexpr int QN = CO*CD;                  // 512 (L1) / 128 (L0)
  constexpr int PSTR = (CD==16) ? 20 : 12;   // part row stride (f32 words), padded
  constexpr int SSTR = (CD==16) ? 12 : 4;    // smat row stride (u32 words), padded

  __shared__ float    part[NW*CO*PSTR];
  __shared__ unsigned smat[CO*SSTR];

  const int b = blockIdx.x;
  const int tid = threadIdx.x;
  const int wv = tid >> 6, lane = tid & 63;
  const int o  = (CO==32) ? ((lane & 15) | (((lane>>5)&1)<<4)) : (lane & 15);
  const int jw = (CO==32) ? ((lane>>4)&1) : (lane>>4);
  const int jj = jw + JPW*wv;

  const f16* __restrict__ ub = uh + (size_t)b*T*NP*CD;
  float* __restrict__ vb = vseq + (size_t)b*T*QN;

  unsigned uoff[SLOTS];
  bool valid[SLOTS];
#pragma unroll
  for (int s=0;s<SLOTS;s++) {
    int n = jj + NJ*s;
    valid[s] = (n < 80);
    if (n >= 80) n = jj;
    uoff[s] = (unsigned)(n*CO + o)*CD;
  }

  union VH { unsigned w[CD/2]; f16x2 h2[CD/2]; uint4 q4[CD/8]; } vh;
#pragma unroll
  for (int q=0;q<CD/2;q++) vh.w[q] = 0u;

  f16x8 Ua[SLOTS][CD/8], Ub[SLOTS][CD/8];

  auto loadu = [&](f16x8 (&U)[SLOTS][CD/8], int tt) {
    const f16* base = ub + (size_t)tt*NP*CD;
#pragma unroll
    for (int s=0;s<SLOTS;s++)
#pragma unroll
      for (int q=0;q<CD/8;q++)
        U[s][q] = *(const f16x8*)(base + uoff[s] + q*8);
  };

  auto step = [&](const f16x8 (&U)[SLOTS][CD/8], int tt) {
    // ---- logits via dot2 (f32 accum)
    float lg[SLOTS];
#pragma unroll
    for (int s=0;s<SLOTS;s++) {
      float a = 0.f;
#pragma unroll
      for (int q=0;q<CD/8;q++) {
        const f16x2* u2 = (const f16x2*)&U[s][q];
#pragma unroll
        for (int z=0;z<4;z++)
          a = __builtin_amdgcn_fdot2(u2[z], vh.h2[q*4+z], a, false);
      }
      if (MASK && o == 0) a -= 1e9f;
      lg[s] = a;
    }
    // ---- softmax over o: VALU-only reductions, slots interleaved
    float mx[SLOTS], ex[SLOTS], sm[SLOTS];
#pragma unroll
    for (int s=0;s<SLOTS;s++) mx[s] = lg[s];
#pragma unroll
    for (int s=0;s<SLOTS;s++) mx[s] = dpp_max<0x121>(mx[s]);
#pragma unroll
    for (int s=0;s<SLOTS;s++) mx[s] = dpp_max<0x122>(mx[s]);
#pragma unroll
    for (int s=0;s<SLOTS;s++) mx[s] = dpp_max<0x124>(mx[s]);
#pragma unroll
    for (int s=0;s<SLOTS;s++) mx[s] = dpp_max<0x128>(mx[s]);
    if (CO == 32) {
#pragma unroll
      for (int s=0;s<SLOTS;s++) mx[s] = pl32_max(mx[s]);
    }
#pragma unroll
    for (int s=0;s<SLOTS;s++) { ex[s] = __expf(lg[s]-mx[s]); sm[s] = ex[s]; }
#pragma unroll
    for (int s=0;s<SLOTS;s++) sm[s] = dpp_add<0x121>(sm[s]);
#pragma unroll
    for (int s=0;s<SLOTS;s++) sm[s] = dpp_add<0x122>(sm[s]);
#pragma unroll
    for (int s=0;s<SLOTS;s++) sm[s] = dpp_add<0x124>(sm[s]);
#pragma unroll
    for (int s=0;s<SLOTS;s++) sm[s] = dpp_add<0x128>(sm[s]);
    if (CO == 32) {
#pragma unroll
      for (int s=0;s<SLOTS;s++) sm[s] = pl32_add(sm[s]);
    }
    // ---- PV partial (per-lane, unique (o,jj))
    float pp[CD];
#pragma unroll
    for (int p=0;p<CD;p++) pp[p] = 0.f;
#pragma unroll
    for (int s=0;s<SLOTS;s++) {
      float c = ex[s] * __builtin_amdgcn_rcpf(sm[s]);
      if (!valid[s]) c = 0.f;
#pragma unroll
      for (int p=0;p<CD;p++) pp[p] += c * (float)U[s][p/8][p&7];
    }
    // ---- in-register jw reduction (VALU cross-lane), then single part row/wave
#pragma unroll
    for (int p=0;p<CD;p++) {
      pp[p] = swap16_add(pp[p]);            // lane^16
      if (CO == 16) pp[p] = pl32_add(pp[p]); // lane^32 (JPW=4)
    }
    if (jw == 0) {
      float* pr = &part[(wv*CO + o)*PSTR];
#pragma unroll
      for (int p=0;p<CD;p+=4) {
        f32x4 w4 = { pp[p], pp[p+1], pp[p+2], pp[p+3] };
        *(f32x4*)(pr + p) = w4;
      }
    }
    lds_barrier();
    // ---- cross-wave reduce + squash + publish (first QN threads)
    if (QN == TH || tid < QN) {
      const int p2 = tid & (CD-1), o2 = tid >> (CD==16 ? 4 : 3);
      float sv = 0.f;
#pragma unroll
      for (int w=0; w<NW; ++w) sv += part[(w*CO + o2)*PSTR + p2];
      float sq = sv*sv;
      if (CD == 16) {
        sq = dpp_add<0x121>(sq); sq = dpp_add<0x122>(sq);
        sq = dpp_add<0x124>(sq); sq = dpp_add<0x128>(sq);
      } else {
        sq = dpp_add<0xB1>(sq); sq = dpp_add<0x4E>(sq); sq = dpp_add<0x141>(sq);
      }
      float f = sq * __builtin_amdgcn_rcpf(1.f + sq) * rsqrtf(sq + 1e-9f);
      float vn = sv * f;
      vb[(size_t)tt*QN + tid] = vn;
      float vn1 = dpp_get<0xB1>(vn);          // value from lane^1
      if ((p2 & 1) == 0) {
        union { f16x2 h2; unsigned w; } pk;
        pk.h2 = (f16x2){ (f16)vn, (f16)vn1 };
        smat[o2*SSTR + (p2>>1)] = pk.w;
      }
    }
    lds_barrier();
#pragma unroll
    for (int q=0;q<CD/8;q++)
      vh.q4[q] = *(const uint4*)&smat[o*SSTR + q*4];
  };

  loadu(Ua, 0);
  for (int t=0; t<T; t+=2) {
    loadu(Ub, (t+1 < T) ? t+1 : t);
    step(Ua, t);
    loadu(Ua, (t+2 < T) ? t+2 : t);
    step(Ub, t+1);
  }
}

// ---------------------------------------------------------------- final: LN512 -> length -> LN32
__global__ __launch_bounds__(512) void k_final(
    const float* __restrict__ v1,
    const float* __restrict__ g1, const float* __restrict__ b1,
    const float* __restrict__ g2, const float* __restrict__ b2,
    float* __restrict__ out)
{
  int bt = blockIdx.x;
  int tid = threadIdx.x;
  float x = v1[(size_t)bt*512 + tid];
  __shared__ float red[16];
  __shared__ float Ls[32];
  float s1 = x, s2 = x*x;
#pragma unroll
  for (int m=1;m<64;m<<=1){ s1 += __shfl_xor(s1,m,64); s2 += __shfl_xor(s2,m,64); }
  if ((tid & 63) == 0){ red[(tid>>6)*2] = s1; red[(tid>>6)*2+1] = s2; }
  __syncthreads();
  float S1 = 0.f, S2 = 0.f;
#pragma unroll
  for (int i=0;i<8;i++){ S1 += red[2*i]; S2 += red[2*i+1]; }
  float mean = S1/512.f, var = S2/512.f - mean*mean;
  float y = (x-mean)*rsqrtf(var+1e-3f)*g1[tid] + b1[tid];
  float ss = y*y;
  ss += __shfl_xor(ss,1,16); ss += __shfl_xor(ss,2,16);
  ss += __shfl_xor(ss,4,16); ss += __shfl_xor(ss,8,16);
  float L = sqrtf(ss + 1e-9f);
  if ((tid & 15) == 0) Ls[tid >> 4] = L;
  __syncthreads();
  if (tid < 32) {
    float l = Ls[tid];
    float t1 = l, t2 = l*l;
#pragma unroll
    for (int m=1;m<32;m<<=1){ t1 += __shfl_xor(t1,m,32); t2 += __shfl_xor(t2,m,32); }
    float mn = t1/32.f, vr = t2/32.f - mn*mn;
    out[(size_t)bt*32 + tid] = (l-mn)*rsqrtf(vr+1e-3f)*g2[tid] + b2[tid];
  }
}

// ---------------------------------------------------------------- workspace layout
static const size_t OFF_X1F   = 0;            // 20,971,520 B f16 [4,1024,40,64]
static const size_t OFF_WT16  = 20971520;     //     77,824 B f16 [64][600]
static const size_t OFF_X2    = 21049344;     // 10,485,760 B f32 [4,512,20,64]
static const size_t OFF_EMB0  = 31535104;     //    131,072 B f32 [4,512,16]
static const size_t OFF_UH0   = 31666176;     // 41,943,040 B f16 [4,512,1280,8]
static const size_t OFF_UH1   = 0;            // 167,772,160 B f16 [4,512,2560,16]
static const size_t OFF_EMBLN = 167772160;    //  1,048,576 B f32 (dead before scan0)
static const size_t OFF_V0    = 167772160;    //  1,048,576 B f32 (reuses EMBLN slot)
static const size_t OFF_V0LN  = 168820736;    //  1,048,576 B f32
static const size_t OFF_V1    = 169869312;    //  4,194,304 B f32 [4,512,32,16]
static const size_t WS_NEED   = 174063616;

extern "C" void kernel_launch(void* const* d_in, const int* in_sizes, int n_in,
                              void* d_out, int out_size, void* d_ws, size_t ws_size,
                              hipStream_t stream) {
  (void)in_sizes; (void)n_in; (void)out_size;
  if (ws_size < WS_NEED) return;

  const float* inputs = (const float*)d_in[0];
  const int*   lens   = (const int*)d_in[1];
  const float* c1w=(const float*)d_in[2],  *c1b=(const float*)d_in[3];
  const float* c2w=(const float*)d_in[4],  *c2b=(const float*)d_in[5];
  const float* pw =(const float*)d_in[6],  *pb =(const float*)d_in[7];
  const float* e0w=(const float*)d_in[8],  *e0b=(const float*)d_in[9];
  const float* e1w=(const float*)d_in[10], *e1b=(const float*)d_in[11];
  const float* lnig=(const float*)d_in[12],*lnib=(const float*)d_in[13];
  const float* W0=(const float*)d_in[14],  *B0=(const float*)d_in[15];
  const float* W1=(const float*)d_in[16],  *B1=(const float*)d_in[17];
  const float* lnm0g=(const float*)d_in[18],*lnm0b=(const float*)d_in[19];
  const float* lnm1g=(const float*)d_in[20],*lnm1b=(const float*)d_in[21];
  const float* lnog=(const float*)d_in[22], *lnob=(const float*)d_in[23];

  char* ws = (char*)d_ws;
  f16*   x1f   = (f16*)  (ws + OFF_X1F);
  f16*   wt16  = (f16*)  (ws + OFF_WT16);
  float* x2    = (float*)(ws + OFF_X2);
  float* emb0  = (float*)(ws + OFF_EMB0);
  f16*   uh0   = (f16*)  (ws + OFF_UH0);
  f16*   uh1   = (f16*)  (ws + OFF_UH1);
  float* embln = (float*)(ws + OFF_EMBLN);
  float* v0    = (float*)(ws + OFF_V0);
  float* v0ln  = (float*)(ws + OFF_V0LN);
  float* v1    = (float*)(ws + OFF_V1);

  k_conv1<<<40960, 256, 0, stream>>>(inputs, c1w, c1b, x1f);
  k_wcvt <<<152, 256, 0, stream>>>(c2w, wt16);
  k_conv2m<<<320, 256, 0, stream>>>(x1f, wt16, c2b, x2);
  k_proj <<<2048, 256, 0, stream>>>(x2, pw, pb, emb0);
  k_primary<<<2048, 128, 0, stream>>>(emb0, e0w, e0b, e1w, e1b, lnig, lnib, lens, embln);
  k_uhat<16,8><<<640, 256, 0, stream>>>(embln, W0, B0, uh0);
  k_scan5<16,8,8,false><<<4, 512, 0, stream>>>(uh0, v0, 512);
  k_ln128<<<2048, 128, 0, stream>>>(v0, lnm0g, lnm0b, v0ln);
  k_uhat<32,16><<<640, 256, 0, stream>>>(v0ln, W1, B1, uh1);
  k_scan5<32,16,8,true><<<4, 512, 0, stream>>>(uh1, v1, 512);
  k_final<<<2048, 512, 0, stream>>>(v1, lnm1g, lnm1b, lnog, lnob, (float*)d_out);
}

// Round 7
// 1845.013 us; speedup vs baseline: 2.0875x; 1.1075x over previous
//
#include <hip/hip_runtime.h>
#include <hip/hip_fp16.h>

typedef _Float16 f16;
typedef _Float16 f16x2 __attribute__((ext_vector_type(2)));
typedef _Float16 f16x8 __attribute__((ext_vector_type(8)));
typedef float f32x4 __attribute__((ext_vector_type(4)));

#define DEV static __device__ __forceinline__

// LDS-only barrier — keeps global loads/stores in flight.
DEV void lds_barrier() {
  asm volatile("s_waitcnt lgkmcnt(0)" ::: "memory");
  __builtin_amdgcn_s_barrier();
  asm volatile("" ::: "memory");
}

// ---- VALU cross-lane reduction helpers (no DS pipe) ----
template<int CTRL>
DEV float dpp_add(float x) {
  int y = __builtin_amdgcn_update_dpp(0, __builtin_bit_cast(int, x), CTRL, 0xf, 0xf, false);
  return x + __builtin_bit_cast(float, y);
}
template<int CTRL>
DEV float dpp_get(float x) {
  int y = __builtin_amdgcn_update_dpp(0, __builtin_bit_cast(int, x), CTRL, 0xf, 0xf, false);
  return __builtin_bit_cast(float, y);
}
DEV float pl32_add(float x) {  // x + x[lane^32]
  unsigned xi = __builtin_bit_cast(unsigned, x);
  auto r = __builtin_amdgcn_permlane32_swap(xi, xi, false, false);
  return __builtin_bit_cast(float, (unsigned)r[0]) + __builtin_bit_cast(float, (unsigned)r[1]);
}
DEV float swap16_add(float x) {  // x + x[lane^16]
#if __has_builtin(__builtin_amdgcn_permlane16_swap)
  unsigned xi = __builtin_bit_cast(unsigned, x);
  auto r = __builtin_amdgcn_permlane16_swap(xi, xi, false, false);
  return __builtin_bit_cast(float, (unsigned)r[0]) + __builtin_bit_cast(float, (unsigned)r[1]);
#else
  int y = __builtin_amdgcn_ds_swizzle(__builtin_bit_cast(int, x), 0x401F);
  return x + __builtin_bit_cast(float, y);
#endif
}

// ---------------------------------------------------------------- conv1
__global__ __launch_bounds__(256) void k_conv1(
    const float* __restrict__ in, const float* __restrict__ w,
    const float* __restrict__ bias, f16* __restrict__ out)
{
  int idx = blockIdx.x*256 + threadIdx.x;
  int co = idx & 63;
  int ow = (idx >> 6) % 40;
  int oh = ((idx >> 6) / 40) % 1024;
  int b  = idx / (64*40*1024);
  float acc = bias[co];
#pragma unroll
  for (int kh=0; kh<3; kh++) {
    int ih = oh*2 + kh;
    if (ih >= 2048) continue;
#pragma unroll
    for (int kw=0; kw<3; kw++) {
      int iw = ow*2 + kw;
      if (iw >= 80) continue;
      acc += in[(b*2048 + ih)*80 + iw] * w[(kh*3+kw)*64 + co];
    }
  }
  out[idx] = (f16)fmaxf(acc, 0.f);
}

// ---------------------------------------------------------------- weight convert+transpose
__global__ __launch_bounds__(256) void k_wcvt(
    const float* __restrict__ w, f16* __restrict__ wt)
{
  int idx = blockIdx.x*256 + threadIdx.x;
  if (idx >= 38912) return;
  f16 v = (f16)0.f;
  if (idx < 38400) {
    int n = idx / 600, k = idx % 600;
    if (k < 576) v = (f16)w[k*64 + n];
  }
  wt[idx] = v;
}

// ---------------------------------------------------------------- conv2 as implicit GEMM (MFMA fp16)
__global__ __launch_bounds__(256) void k_conv2m(
    const f16* __restrict__ x1f, const f16* __restrict__ wt,
    const float* __restrict__ bias, float* __restrict__ out)
{
  __shared__ f16 Bt[38912];
  const int tid = threadIdx.x;
  for (int it = 0; it < 19; ++it) {
    const f16* g = wt + it*2048 + tid*8;
    f16* l = Bt + it*2048 + tid*8;
    __builtin_amdgcn_global_load_lds(
        (const __attribute__((address_space(1))) void*)g,
        (__attribute__((address_space(3))) void*)l, 16, 0, 0);
  }
  __syncthreads();

  const int wave = tid >> 6, l = tid & 63;
  const int lrow = l & 15, lk = l >> 4;
  const int m0 = blockIdx.x*128 + wave*32;

  const int mA = m0 + lrow, mB = m0 + 16 + lrow;
  int bA = mA/10240, rA = mA%10240, ohA = rA/20, owA = rA%20;
  int bB = mB/10240, rB = mB%10240, ohB = rB/20, owB = rB%20;
  const f16* pA = x1f + ((size_t)((bA*1024 + ohA*2)*40 + owA*2))*64;
  const f16* pB = x1f + ((size_t)((bB*1024 + ohB*2)*40 + owB*2))*64;

  f32x4 acc[2][4];
#pragma unroll
  for (int i=0;i<2;i++)
#pragma unroll
    for (int j=0;j<4;j++) acc[i][j] = (f32x4){0.f,0.f,0.f,0.f};

  const f16x8 zero8 = {};
#pragma unroll
  for (int kk=0; kk<18; ++kk) {
    const int tap = kk >> 1;
    const int kh = tap/3, kw = tap%3;
    const int ci0 = ((kk&1)<<5) + lk*8;
    const int off = (kh*40 + kw)*64 + ci0;
    const bool okA = (ohA*2+kh < 1024) && (owA*2+kw < 40);
    const bool okB = (ohB*2+kh < 1024) && (owB*2+kw < 40);
    f16x8 a0 = okA ? *(const f16x8*)(pA + off) : zero8;
    f16x8 a1 = okB ? *(const f16x8*)(pB + off) : zero8;
#pragma unroll
    for (int nf=0; nf<4; ++nf) {
      f16x8 bb = *(const f16x8*)&Bt[(nf*16 + lrow)*600 + kk*32 + lk*8];
      acc[0][nf] = __builtin_amdgcn_mfma_f32_16x16x32_f16(a0, bb, acc[0][nf], 0,0,0);
      acc[1][nf] = __builtin_amdgcn_mfma_f32_16x16x32_f16(a1, bb, acc[1][nf], 0,0,0);
    }
  }
#pragma unroll
  for (int nf=0; nf<4; ++nf) {
    const int n = nf*16 + lrow;
    const float bi = bias[n];
#pragma unroll
    for (int mf=0; mf<2; ++mf)
#pragma unroll
      for (int r=0; r<4; ++r) {
        int mrow = m0 + mf*16 + lk*4 + r;
        out[(size_t)mrow*64 + n] = fmaxf(acc[mf][nf][r] + bi, 0.f);
      }
  }
}

// ---------------------------------------------------------------- proj
__global__ __launch_bounds__(256) void k_proj(
    const float* __restrict__ x, const float* __restrict__ pw,
    const float* __restrict__ pb, float* __restrict__ out)
{
  int bt = blockIdx.x;
  int tid = threadIdx.x;
  int j = tid >> 4;
  int l = tid & 15;
  const float* xr = x + (size_t)bt*1280;
  float s = 0.f;
  for (int k=0; k<80; k++) {
    int f = l + 16*k;
    s += xr[f] * pw[f*16 + j];
  }
  s += __shfl_xor(s, 1, 16); s += __shfl_xor(s, 2, 16);
  s += __shfl_xor(s, 4, 16); s += __shfl_xor(s, 8, 16);
  if (l == 0) out[bt*16 + j] = s + pb[j];
}

// ------------------------------------------- primary caps
__global__ __launch_bounds__(128) void k_primary(
    const float* __restrict__ emb0,
    const float* __restrict__ w0, const float* __restrict__ b0,
    const float* __restrict__ w1, const float* __restrict__ b1,
    const float* __restrict__ g, const float* __restrict__ be,
    const int* __restrict__ lens, float* __restrict__ out)
{
  int bt = blockIdx.x;
  int b = bt >> 9, t = bt & 511;
  int tid = threadIdx.x;
  int c = tid & 7, j = tid >> 3;
  __shared__ float rows[3][16];
  __shared__ float red[4];
  if (tid < 48) {
    int kh = tid / 16, jj = tid % 16;
    int ts = t + kh - 1;
    rows[kh][jj] = (ts >= 0 && ts < 512) ? emb0[(b*512+ts)*16 + jj] : 0.f;
  }
  __syncthreads();
  float a0 = b0[c], a1 = b1[c];
#pragma unroll
  for (int kh=0; kh<3; kh++)
#pragma unroll
    for (int kw=0; kw<3; kw++) {
      int jj = j + kw - 1;
      if (jj < 0 || jj >= 16) continue;
      float xv = rows[kh][jj];
      a0 += xv * w0[(kh*3+kw)*8 + c];
      a1 += xv * w1[(kh*3+kw)*8 + c];
    }
  float e = fmaxf(a0, a1);
  int valid = (lens[b] + 3) >> 2;
  if (t >= valid) e = 0.f;
  float sq = e*e;
  sq += __shfl_xor(sq, 1, 8); sq += __shfl_xor(sq, 2, 8); sq += __shfl_xor(sq, 4, 8);
  float val = e * (sq / (1.f + sq)) * rsqrtf(sq + 1e-9f);
  float s1 = val, s2 = val*val;
#pragma unroll
  for (int m=1;m<64;m<<=1){ s1 += __shfl_xor(s1,m,64); s2 += __shfl_xor(s2,m,64); }
  if ((tid & 63) == 0){ red[(tid>>6)*2] = s1; red[(tid>>6)*2+1] = s2; }
  __syncthreads();
  float S1 = red[0]+red[2], S2 = red[1]+red[3];
  float mean = S1/128.f;
  float var  = S2/128.f - mean*mean;
  out[(size_t)bt*128 + tid] = (val-mean)*rsqrtf(var+1e-3f)*g[tid] + be[tid];
}

// ---------------------------------------------------------------- generic LN over 128
__global__ __launch_bounds__(128) void k_ln128(
    const float* __restrict__ in, const float* __restrict__ g,
    const float* __restrict__ be, float* __restrict__ out)
{
  int bt = blockIdx.x, tid = threadIdx.x;
  float x = in[(size_t)bt*128 + tid];
  __shared__ float red[4];
  float s1 = x, s2 = x*x;
#pragma unroll
  for (int m=1;m<64;m<<=1){ s1 += __shfl_xor(s1,m,64); s2 += __shfl_xor(s2,m,64); }
  if ((tid & 63) == 0){ red[(tid>>6)*2] = s1; red[(tid>>6)*2+1] = s2; }
  __syncthreads();
  float S1 = red[0]+red[2], S2 = red[1]+red[3];
  float mean = S1/128.f;
  float var  = S2/128.f - mean*mean;
  out[(size_t)bt*128 + tid] = (x-mean)*rsqrtf(var+1e-3f)*g[tid] + be[tid];
}

// ---------------------------------------------------------------- u_hat precompute
template<int CO, int CD>
__global__ __launch_bounds__(256) void k_uhat(
    const float* __restrict__ src, const float* __restrict__ W,
    const float* __restrict__ Bs, f16* __restrict__ out)
{
  constexpr int NP = 80*CO;
  int wid = __builtin_amdgcn_readfirstlane(blockIdx.x*4 + (threadIdx.x >> 6));
  int lane = threadIdx.x & 63;
  int n   = wid % 80;
  int btc = wid / 80;
  int bt = btc*64 + lane;
  int b = bt >> 9, t = bt & 511;
  int k = n >> 4, i = n & 15;
  int ts = t + k - 2;
  float x[8];
  if (ts >= 0 && ts < 512) {
    const float* xr = src + ((size_t)(b*512+ts)*16 + i)*8;
    f32x4 x0 = *(const f32x4*)xr;
    f32x4 x1 = *(const f32x4*)(xr+4);
#pragma unroll
    for (int q=0;q<4;q++){ x[q]=x0[q]; x[4+q]=x1[q]; }
  } else {
#pragma unroll
    for (int q=0;q<8;q++) x[q]=0.f;
  }
  const float* Wn = W  + (size_t)n*CO*CD*8;
  const float* Bn = Bs + (size_t)n*CO*CD;
  for (int o=0; o<CO; o++) {
    alignas(16) f16 res[CD];
#pragma unroll
    for (int p=0;p<CD;p++) {
      float a = Bn[o*CD+p];
#pragma unroll
      for (int q=0;q<8;q++) a += Wn[(o*CD+p)*8+q]*x[q];
      res[p] = (f16)a;
    }
    f16* op = out + ((size_t)bt*NP + (size_t)n*CO + o)*CD;
    *(uint4*)op = *(const uint4*)res;
    if constexpr (CD==16) *((uint4*)op+1) = *((const uint4*)res+1);
  }
}

// ---------------------------------------------------------------- routing scan v6
// Register-resident u tiles (macro-expanded, constant-indexed arrays — no lambda
// refs; fixes the v4/v5 SROA failure that left VGPR=48 and re-loaded every tile
// twice from memory). Pointer-bump main loop (no clamps; 1-tile overread lands in
// owned ws). Softmax WITHOUT max-subtract (|logits| <~ 8, exp safe in f32; mask
// via ex=0). All cross-lane math on VALU (DPP/permlane).
template<int CO, int CD, int NW, bool MASK>
__global__ __launch_bounds__(NW*64, 1) void k_scan6(
    const f16* __restrict__ uh, float* __restrict__ vseq, int T)
{
  constexpr int TH = NW*64;
  constexpr int JPW = 64/CO;                 // jj groups per wave (2 or 4)
  constexpr int NJ  = NW*JPW;                // 16 (L1) or 32 (L0)
  constexpr int SLOTS = (80 + NJ - 1)/NJ;    // 5 (L1) or 3 (L0)
  constexpr int NP = 80*CO;
  constexpr int QN = CO*CD;                  // 512 (L1) / 128 (L0)
  constexpr int NV = CD/8;
  constexpr int PSTR = (CD==16) ? 20 : 12;   // part row stride (f32), padded
  constexpr int SSTR = (CD==16) ? 12 : 4;    // smat row stride (u32)

  __shared__ float    part[NW*CO*PSTR];
  __shared__ unsigned smat[CO*SSTR];

  const int b = blockIdx.x;
  const int tid = threadIdx.x;
  const int wv = tid >> 6, lane = tid & 63;
  const int o  = (CO==32) ? ((lane & 15) | (((lane>>5)&1)<<4)) : (lane & 15);
  const int jw = (CO==32) ? ((lane>>4)&1) : (lane>>4);
  const int jj = jw + JPW*wv;

  const f16* __restrict__ ubase = uh + (size_t)b*T*NP*CD;
  float* __restrict__ vb = vseq + (size_t)b*T*QN;

  unsigned uoff[SLOTS];
#pragma unroll
  for (int s=0;s<SLOTS;s++) {
    int n = jj + NJ*s;
    if (n >= 80) n = jj;                     // clamp (loads stay in-bounds; result zeroed)
    uoff[s] = (unsigned)(n*CO + o)*CD;
  }
  // last-slot validity (only scan0 has a partial slot)
  const bool lastValid = (SLOTS*NJ <= 80) || (jj < 80 - NJ*(SLOTS-1));

  union VHU { unsigned w[CD/2]; f16x2 h2[CD/2]; uint4 q4[NV]; } vh;
#pragma unroll
  for (int q=0;q<CD/2;q++) vh.w[q] = 0u;

  f16x8 UA[SLOTS][NV], UB[SLOTS][NV];

#define LOADU(U, PTR) do {                                                   \
  _Pragma("unroll") for (int s_=0; s_<SLOTS; ++s_)                           \
  _Pragma("unroll") for (int q_=0; q_<NV; ++q_)                              \
    U[s_][q_] = *(const f16x8*)((PTR) + uoff[s_] + q_*8);                    \
} while(0)

#define STEP(U, TT) do {                                                     \
  float c_[SLOTS];                                                           \
  _Pragma("unroll") for (int s_=0; s_<SLOTS; ++s_) {                         \
    float a_ = 0.f;                                                          \
    _Pragma("unroll") for (int q_=0; q_<NV; ++q_) {                          \
      const f16x2* u2_ = (const f16x2*)&U[s_][q_];                           \
      _Pragma("unroll") for (int z_=0; z_<4; ++z_)                           \
        a_ = __builtin_amdgcn_fdot2(u2_[z_], vh.h2[q_*4+z_], a_, false);     \
    }                                                                        \
    float ex_ = __expf(a_);                                                  \
    if (MASK && o == 0) ex_ = 0.f;                                           \
    float sm_ = ex_;                                                         \
    sm_ = dpp_add<0x121>(sm_); sm_ = dpp_add<0x122>(sm_);                    \
    sm_ = dpp_add<0x124>(sm_); sm_ = dpp_add<0x128>(sm_);                    \
    if (CO == 32) sm_ = pl32_add(sm_);                                       \
    c_[s_] = ex_ * __builtin_amdgcn_rcpf(sm_);                               \
    if (s_ == SLOTS-1 && !lastValid) c_[s_] = 0.f;                           \
  }                                                                          \
  float pp_[CD];                                                             \
  _Pragma("unroll") for (int p_=0; p_<CD; ++p_) pp_[p_] = 0.f;               \
  _Pragma("unroll") for (int s_=0; s_<SLOTS; ++s_)                           \
  _Pragma("unroll") for (int p_=0; p_<CD; ++p_)                              \
    pp_[p_] += (float)U[s_][p_/8][p_&7] * c_[s_];                            \
  _Pragma("unroll") for (int p_=0; p_<CD; ++p_) {                            \
    pp_[p_] = swap16_add(pp_[p_]);                                           \
    if (CO == 16) pp_[p_] = pl32_add(pp_[p_]);                               \
  }                                                                          \
  if (jw == 0) {                                                             \
    float* pr_ = &part[(wv*CO + o)*PSTR];                                    \
    _Pragma("unroll") for (int p_=0; p_<CD; p_+=4) {                         \
      f32x4 w4_ = { pp_[p_], pp_[p_+1], pp_[p_+2], pp_[p_+3] };              \
      *(f32x4*)(pr_ + p_) = w4_;                                             \
    }                                                                        \
  }                                                                          \
  lds_barrier();                                                             \
  if (QN == TH || tid < QN) {                                                \
    const int p2_ = tid & (CD-1), o2_ = tid >> ((CD==16)?4:3);               \
    float sv_ = 0.f;                                                         \
    _Pragma("unroll") for (int w_=0; w_<NW; ++w_)                            \
      sv_ += part[(w_*CO + o2_)*PSTR + p2_];                                 \
    float sq_ = sv_*sv_;                                                     \
    if (CD == 16) {                                                          \
      sq_ = dpp_add<0x121>(sq_); sq_ = dpp_add<0x122>(sq_);                  \
      sq_ = dpp_add<0x124>(sq_); sq_ = dpp_add<0x128>(sq_);                  \
    } else {                                                                 \
      sq_ = dpp_add<0xB1>(sq_); sq_ = dpp_add<0x4E>(sq_);                    \
      sq_ = dpp_add<0x141>(sq_);                                             \
    }                                                                        \
    float f_ = sq_ * __builtin_amdgcn_rcpf(1.f + sq_) * rsqrtf(sq_ + 1e-9f); \
    float vn_ = sv_ * f_;                                                    \
    vb[(size_t)(TT)*QN + tid] = vn_;                                         \
    float vn1_ = dpp_get<0xB1>(vn_);                                         \
    if ((p2_ & 1) == 0) {                                                    \
      union { f16x2 h2; unsigned w; } pk_;                                   \
      pk_.h2 = (f16x2){ (f16)vn_, (f16)vn1_ };                               \
      smat[o2_*SSTR + (p2_>>1)] = pk_.w;                                     \
    }                                                                        \
  }                                                                          \
  lds_barrier();                                                             \
  _Pragma("unroll") for (int q_=0; q_<NV; ++q_)                              \
    vh.q4[q_] = *(const uint4*)&smat[o*SSTR + q_*4];                         \
} while(0)

  const size_t ST = (size_t)NP*CD;
  const f16* pcur = ubase;
  LOADU(UA, pcur);
  for (int t=0; t<T; t+=2) {
    LOADU(UB, pcur + ST);          // tile t+1
    STEP(UA, t);
    LOADU(UA, pcur + 2*ST);        // tile t+2 (tail overread stays in ws)
    STEP(UB, t+1);
    pcur += 2*ST;
  }
#undef LOADU
#undef STEP
}

// ---------------------------------------------------------------- final: LN512 -> length -> LN32
__global__ __launch_bounds__(512) void k_final(
    const float* __restrict__ v1,
    const float* __restrict__ g1, const float* __restrict__ b1,
    const float* __restrict__ g2, const float* __restrict__ b2,
    float* __restrict__ out)
{
  int bt = blockIdx.x;
  int tid = threadIdx.x;
  float x = v1[(size_t)bt*512 + tid];
  __shared__ float red[16];
  __shared__ float Ls[32];
  float s1 = x, s2 = x*x;
#pragma unroll
  for (int m=1;m<64;m<<=1){ s1 += __shfl_xor(s1,m,64); s2 += __shfl_xor(s2,m,64); }
  if ((tid & 63) == 0){ red[(tid>>6)*2] = s1; red[(tid>>6)*2+1] = s2; }
  __syncthreads();
  float S1 = 0.f, S2 = 0.f;
#pragma unroll
  for (int i=0;i<8;i++){ S1 += red[2*i]; S2 += red[2*i+1]; }
  float mean = S1/512.f, var = S2/512.f - mean*mean;
  float y = (x-mean)*rsqrtf(var+1e-3f)*g1[tid] + b1[tid];
  float ss = y*y;
  ss += __shfl_xor(ss,1,16); ss += __shfl_xor(ss,2,16);
  ss += __shfl_xor(ss,4,16); ss += __shfl_xor(ss,8,16);
  float L = sqrtf(ss + 1e-9f);
  if ((tid & 15) == 0) Ls[tid >> 4] = L;
  __syncthreads();
  if (tid < 32) {
    float l = Ls[tid];
    float t1 = l, t2 = l*l;
#pragma unroll
    for (int m=1;m<32;m<<=1){ t1 += __shfl_xor(t1,m,32); t2 += __shfl_xor(t2,m,32); }
    float mn = t1/32.f, vr = t2/32.f - mn*mn;
    out[(size_t)bt*32 + tid] = (l-mn)*rsqrtf(vr+1e-3f)*g2[tid] + b2[tid];
  }
}

// ---------------------------------------------------------------- workspace layout
static const size_t OFF_X1F   = 0;            // 20,971,520 B f16 [4,1024,40,64]
static const size_t OFF_WT16  = 20971520;     //     77,824 B f16 [64][600]
static const size_t OFF_X2    = 21049344;     // 10,485,760 B f32 [4,512,20,64]
static const size_t OFF_EMB0  = 31535104;     //    131,072 B f32 [4,512,16]
static const size_t OFF_UH0   = 31666176;     // 41,943,040 B f16 [4,512,1280,8]
static const size_t OFF_UH1   = 0;            // 167,772,160 B f16 [4,512,2560,16]
static const size_t OFF_EMBLN = 167772160;    //  1,048,576 B f32 (dead before scan0)
static const size_t OFF_V0    = 167772160;    //  1,048,576 B f32 (reuses EMBLN slot)
static const size_t OFF_V0LN  = 168820736;    //  1,048,576 B f32
static const size_t OFF_V1    = 169869312;    //  4,194,304 B f32 [4,512,32,16]
static const size_t WS_NEED   = 174063616;

extern "C" void kernel_launch(void* const* d_in, const int* in_sizes, int n_in,
                              void* d_out, int out_size, void* d_ws, size_t ws_size,
                              hipStream_t stream) {
  (void)in_sizes; (void)n_in; (void)out_size;
  if (ws_size < WS_NEED) return;

  const float* inputs = (const float*)d_in[0];
  const int*   lens   = (const int*)d_in[1];
  const float* c1w=(const float*)d_in[2],  *c1b=(const float*)d_in[3];
  const float* c2w=(const float*)d_in[4],  *c2b=(const float*)d_in[5];
  const float* pw =(const float*)d_in[6],  *pb =(const float*)d_in[7];
  const float* e0w=(const float*)d_in[8],  *e0b=(const float*)d_in[9];
  const float* e1w=(const float*)d_in[10], *e1b=(const float*)d_in[11];
  const float* lnig=(const float*)d_in[12],*lnib=(const float*)d_in[13];
  const float* W0=(const float*)d_in[14],  *B0=(const float*)d_in[15];
  const float* W1=(const float*)d_in[16],  *B1=(const float*)d_in[17];
  const float* lnm0g=(const float*)d_in[18],*lnm0b=(const float*)d_in[19];
  const float* lnm1g=(const float*)d_in[20],*lnm1b=(const float*)d_in[21];
  const float* lnog=(const float*)d_in[22], *lnob=(const float*)d_in[23];

  char* ws = (char*)d_ws;
  f16*   x1f   = (f16*)  (ws + OFF_X1F);
  f16*   wt16  = (f16*)  (ws + OFF_WT16);
  float* x2    = (float*)(ws + OFF_X2);
  float* emb0  = (float*)(ws + OFF_EMB0);
  f16*   uh0   = (f16*)  (ws + OFF_UH0);
  f16*   uh1   = (f16*)  (ws + OFF_UH1);
  float* embln = (float*)(ws + OFF_EMBLN);
  float* v0    = (float*)(ws + OFF_V0);
  float* v0ln  = (float*)(ws + OFF_V0LN);
  float* v1    = (float*)(ws + OFF_V1);

  k_conv1<<<40960, 256, 0, stream>>>(inputs, c1w, c1b, x1f);
  k_wcvt <<<152, 256, 0, stream>>>(c2w, wt16);
  k_conv2m<<<320, 256, 0, stream>>>(x1f, wt16, c2b, x2);
  k_proj <<<2048, 256, 0, stream>>>(x2, pw, pb, emb0);
  k_primary<<<2048, 128, 0, stream>>>(emb0, e0w, e0b, e1w, e1b, lnig, lnib, lens, embln);
  k_uhat<16,8><<<640, 256, 0, stream>>>(embln, W0, B0, uh0);
  k_scan6<16,8,8,false><<<4, 512, 0, stream>>>(uh0, v0, 512);
  k_ln128<<<2048, 128, 0, stream>>>(v0, lnm0g, lnm0b, v0ln);
  k_uhat<32,16><<<640, 256, 0, stream>>>(v0ln, W1, B1, uh1);
  k_scan6<32,16,8,true><<<4, 512, 0, stream>>>(uh1, v1, 512);
  k_final<<<2048, 512, 0, stream>>>(v1, lnm1g, lnm1b, lnog, lnob, (float*)d_out);
}